// Round 2
// baseline (7521.446 us; speedup 1.0000x reference)
//
#include <hip/hip_runtime.h>
#include <math.h>

#define NCHUNK 32

__device__ __forceinline__ float gelu_f(float v){
  return 0.5f*v*(1.0f+erff(v*0.70710678118654752440f));
}

// ---------------- kNN in 3D (queries optionally gathered via qidx) ----------------
template<int K>
__global__ __launch_bounds__(256) void knn3_kernel(
    const float* __restrict__ cand, int n,
    const float* __restrict__ qsrc, const int* __restrict__ qidx,
    int m, int* __restrict__ nbr)
{
  __shared__ float cx[1024], cy[1024], cz[1024], cbb[1024];
  int b = blockIdx.y;
  int q = blockIdx.x*256 + threadIdx.x;
  const float* cb = cand + (size_t)b*3*n;
  bool act = q < m;
  float qx=0,qy=0,qz=0,aa=0;
  if (act) {
    int qi = qidx ? qidx[(size_t)b*m + q] : q;
    const float* qb = qsrc + (size_t)b*3*n;
    qx = qb[qi]; qy = qb[n+qi]; qz = qb[2*n+qi];
    aa = (qx*qx + qy*qy) + qz*qz;
  }
  float kd[K]; int ki[K];
  #pragma unroll
  for (int k=0;k<K;k++){ kd[k]=1e30f; ki[k]=0x7fffffff; }
  float wd = 1e30f; int wslot = 0, wi = 0x7fffffff;
  for (int base=0; base<n; base+=1024) {
    int cnt = min(1024, n-base);
    for (int j=threadIdx.x; j<cnt; j+=256) {
      float x = cb[base+j], y = cb[n+base+j], z = cb[2*n+base+j];
      cx[j]=x; cy[j]=y; cz[j]=z; cbb[j]=(x*x+y*y)+z*z;
    }
    __syncthreads();
    if (act) {
      for (int j=0;j<cnt;j++) {
        float d = aa + cbb[j] - 2.0f*((qx*cx[j]+qy*cy[j])+qz*cz[j]);
        if (d < wd) {
          int jj = base+j;
          #pragma unroll
          for (int k=0;k<K;k++) if (k==wslot){ kd[k]=d; ki[k]=jj; }
          wd=-1e38f; wi=-1;
          #pragma unroll
          for (int k=0;k<K;k++){
            bool g = (kd[k] > wd) || (kd[k]==wd && ki[k] > wi);
            if (g){ wd=kd[k]; wi=ki[k]; wslot=k; }
          }
        }
      }
    }
    __syncthreads();
  }
  if (act) {
    #pragma unroll
    for (int a=0;a<K-1;a++)
      #pragma unroll
      for (int c=0;c<K-1-a;c++) {
        bool sw = (kd[c] > kd[c+1]) || (kd[c]==kd[c+1] && ki[c] > ki[c+1]);
        if (sw) { float td=kd[c]; kd[c]=kd[c+1]; kd[c+1]=td;
                  int ti=ki[c]; ki[c]=ki[c+1]; ki[c+1]=ti; }
      }
    int* o = nbr + ((size_t)b*m + q)*K;
    #pragma unroll
    for (int k=0;k<K;k++) o[k] = ki[k];
  }
}

// ---------------- farthest point sampling (sequential argmax chain) ----------------
template<int P, int T>
__global__ __launch_bounds__(T) void fps_kernel(const float* __restrict__ cur, int n, int m,
                                                int* __restrict__ sind)
{
  int b = blockIdx.x, tid = threadIdx.x;
  const float* cb = cur + (size_t)b*3*n;
  float px[P], py[P], pz[P], dmin[P];
  #pragma unroll
  for (int s=0;s<P;s++){
    int j = tid + s*T;
    if (j < n) { px[s]=cb[j]; py[s]=cb[n+j]; pz[s]=cb[2*n+j]; dmin[s]=1e30f; }
    else { px[s]=0; py[s]=0; pz[s]=0; dmin[s]=-1e30f; }
  }
  __shared__ float sx, sy, sz;
  __shared__ float wv[T/64]; __shared__ int wiA[T/64]; __shared__ int swi;
  if (tid==0){ sind[(size_t)b*m] = 0; sx=cb[0]; sy=cb[n]; sz=cb[2*n]; }
  __syncthreads();
  for (int step=1; step<m; step++) {
    float X=sx, Y=sy, Z=sz;
    float bv = -1e38f; int bi = 0;
    #pragma unroll
    for (int s=0;s<P;s++){
      float dx=px[s]-X, dy=py[s]-Y, dz=pz[s]-Z;
      float d = (dx*dx + dy*dy) + dz*dz;
      float nd = fminf(dmin[s], d);
      dmin[s] = nd;
      if (nd > bv) { bv = nd; bi = tid + s*T; }
    }
    #pragma unroll
    for (int off=32; off>=1; off>>=1){
      float ov = __shfl_xor(bv, off);
      int   oi = __shfl_xor(bi, off);
      if (ov > bv || (ov==bv && oi < bi)) { bv=ov; bi=oi; }
    }
    if ((tid & 63)==0){ wv[tid>>6]=bv; wiA[tid>>6]=bi; }
    __syncthreads();
    if (tid==0){
      float gv = wv[0]; int gi = wiA[0];
      #pragma unroll
      for (int w=1;w<T/64;w++){
        if (wv[w] > gv || (wv[w]==gv && wiA[w] < gi)) { gv=wv[w]; gi=wiA[w]; }
      }
      sind[(size_t)b*m + step] = gi;
      swi = gi;
    }
    __syncthreads();
    int widx = swi;
    if ((widx % T) == tid) {
      int s = widx / T;
      #pragma unroll
      for (int ss=0; ss<P; ss++) if (ss==s){ sx=px[ss]; sy=py[ss]; sz=pz[ss]; }
    }
    __syncthreads();
  }
}

// ---------------- tiled NT GEMM: out[r,o] = sum_f A[r,f]*Bval(o,f) ----------------
// DUAL: out0 uses B[o*ldb+f], out1 uses (B[o*ldb+boff+f]-B[o*ldb+f])
template<bool DUAL>
__global__ __launch_bounds__(256) void gemm_nt(
    const float* __restrict__ A, const float* __restrict__ B,
    float* __restrict__ out0, float* __restrict__ out1,
    int M, int N, int Kd, int lda, int ldb, int ldo, int boff,
    long sA, long sB, long sO)
{
  int bz = blockIdx.z;
  A += (size_t)bz * sA; B += (size_t)bz * sB;
  float* o0 = out0 + (size_t)bz * sO;
  float* o1 = DUAL ? (out1 + (size_t)bz * sO) : nullptr;
  int rowBase = blockIdx.y*64, colBase = blockIdx.x*64;
  __shared__ float As[16][64], Bs0[16][64];
  __shared__ float Bs1[DUAL?16:1][64];
  int tid = threadIdx.x;
  int ty = tid>>4, tx = tid&15;
  float acc0[4][4] = {}, acc1[4][4] = {};
  int lr = tid>>2, lk = (tid&3)*4;
  for (int k0=0; k0<Kd; k0+=16) {
    float4 va = make_float4(0,0,0,0);
    int r = rowBase + lr;
    if (r < M) va = *(const float4*)(A + (size_t)r*lda + k0 + lk);
    As[lk+0][lr]=va.x; As[lk+1][lr]=va.y; As[lk+2][lr]=va.z; As[lk+3][lr]=va.w;
    float4 vb = make_float4(0,0,0,0), vb2 = make_float4(0,0,0,0);
    int c = colBase + lr;
    if (c < N) {
      vb = *(const float4*)(B + (size_t)c*ldb + k0 + lk);
      if (DUAL) vb2 = *(const float4*)(B + (size_t)c*ldb + boff + k0 + lk);
    }
    Bs0[lk+0][lr]=vb.x; Bs0[lk+1][lr]=vb.y; Bs0[lk+2][lr]=vb.z; Bs0[lk+3][lr]=vb.w;
    if (DUAL) {
      Bs1[lk+0][lr]=vb2.x-vb.x; Bs1[lk+1][lr]=vb2.y-vb.y;
      Bs1[lk+2][lr]=vb2.z-vb.z; Bs1[lk+3][lr]=vb2.w-vb.w;
    }
    __syncthreads();
    #pragma unroll
    for (int kk=0;kk<16;kk++){
      float4 a  = *(const float4*)&As[kk][ty*4];
      float4 b0 = *(const float4*)&Bs0[kk][tx*4];
      float av[4]={a.x,a.y,a.z,a.w};
      float b0v[4]={b0.x,b0.y,b0.z,b0.w};
      #pragma unroll
      for (int i=0;i<4;i++)
        #pragma unroll
        for (int j=0;j<4;j++) acc0[i][j] = fmaf(av[i], b0v[j], acc0[i][j]);
      if (DUAL) {
        float4 b1 = *(const float4*)&Bs1[kk][tx*4];
        float b1v[4]={b1.x,b1.y,b1.z,b1.w};
        #pragma unroll
        for (int i=0;i<4;i++)
          #pragma unroll
          for (int j=0;j<4;j++) acc1[i][j] = fmaf(av[i], b1v[j], acc1[i][j]);
      }
    }
    __syncthreads();
  }
  #pragma unroll
  for (int i=0;i<4;i++){
    int r = rowBase + ty*4 + i;
    if (r < M) {
      #pragma unroll
      for (int j=0;j<4;j++){
        int c = colBase + tx*4 + j;
        if (c < N) {
          o0[(size_t)r*ldo + c] = acc0[i][j];
          if (DUAL) o1[(size_t)r*ldo + c] = acc1[i][j];
        }
      }
    }
  }
}

// ---------------- gather + max over K neighbors (+ optional adds) ----------------
__global__ __launch_bounds__(256) void gathermax_kernel(
    const float* __restrict__ P, const int* __restrict__ nbr,
    const float* __restrict__ addA, const float* __restrict__ addB,
    float* __restrict__ out, int n_out, int n_src, int O, int K, int total)
{
  int e = blockIdx.x*256 + threadIdx.x;
  if (e >= total) return;
  int o = e % O; int r = e / O;
  int b = r / n_out; int i = r % n_out;
  const int* nb = nbr + ((size_t)b*n_out + i)*K;
  float mx = -1e38f;
  for (int k=0;k<K;k++){
    int j = nb[k];
    float v = P[((size_t)b*n_src + j)*O + o];
    mx = fmaxf(mx, v);
  }
  float res = mx;
  if (addA) res += addA[e];
  if (addB) res = addB[e] + res;
  out[e] = res;
}

// ---------------- deterministic per-channel stats: partial pass ----------------
// blockDim.x == O, gridDim.x == NCHUNK
__global__ void stats_part_kernel(const float* __restrict__ x, int R, int O,
                                  float* __restrict__ part)
{
  int o = threadIdx.x;
  int chunk = blockIdx.x;
  int per = (R + NCHUNK - 1)/NCHUNK;
  int r0 = chunk*per, r1 = min(r0+per, R);
  float s=0, q=0;
  for (int r=r0; r<r1; r++){ float v = x[(size_t)r*O + o]; s+=v; q+=v*v; }
  part[(size_t)chunk*1024 + o] = s;
  part[(size_t)(NCHUNK+chunk)*1024 + o] = q;
}

// blockDim.x == O, 1 block; fixed-order sum over chunks -> deterministic
__global__ void stats_final_kernel(const float* __restrict__ part, float* __restrict__ st)
{
  int o = threadIdx.x;
  float s=0, q=0;
  #pragma unroll 4
  for (int c=0;c<NCHUNK;c++){
    s += part[(size_t)c*1024 + o];
    q += part[(size_t)(NCHUNK+c)*1024 + o];
  }
  st[o] = s; st[512+o] = q;
}

__global__ __launch_bounds__(256) void bngelu_kernel(float* __restrict__ x,
    const float* __restrict__ st, float invR, int O, int total)
{
  int e = blockIdx.x*256 + threadIdx.x;
  if (e >= total) return;
  int o = e % O;
  float mu = st[o]*invR;
  float var = st[512+o]*invR - mu*mu;
  float v = (x[e]-mu) / sqrtf(var + 1e-5f);
  x[e] = gelu_f(v);
}

// ---------------- initial 3->64 MLP ----------------
__global__ __launch_bounds__(256) void mlp_kernel(const float* __restrict__ x,
    const float* __restrict__ w, const float* __restrict__ bias,
    float* __restrict__ out, int N, int total)
{
  int e = blockIdx.x*256 + threadIdx.x;
  if (e >= total) return;
  int o = e & 63; int r = e >> 6;
  int b = r / N; int i = r % N;
  const float* xb = x + (size_t)b*3*N;
  float v = ((w[o*3+0]*xb[i] + w[o*3+1]*xb[N+i]) + w[o*3+2]*xb[2*N+i]) + bias[o];
  out[e] = v;
}

// ---------------- mean over 8 neighbors for xyz downsample ----------------
__global__ __launch_bounds__(256) void cur_mean_kernel(const float* __restrict__ cur,
    const int* __restrict__ nbr, float* __restrict__ outc, int n, int m, int total)
{
  int e = blockIdx.x*256 + threadIdx.x;
  if (e >= total) return;
  int i = e % m; int d = (e/m)%3; int b = e/(3*m);
  const int* nb = nbr + ((size_t)b*m + i)*8;
  const float* cb = cur + (size_t)b*3*n + (size_t)d*n;
  float s=0;
  #pragma unroll
  for (int k=0;k<8;k++) s += cb[nb[k]];
  outc[(size_t)b*3*m + (size_t)d*m + i] = s * 0.125f;
}

// ---------------- per-point squared norms ----------------
__global__ __launch_bounds__(256) void norms_kernel(const float* __restrict__ h,
    float* __restrict__ aa, int C, int total)
{
  int e = blockIdx.x*256 + threadIdx.x;
  if (e >= total) return;
  const float* r = h + (size_t)e*C;
  float s=0;
  for (int c=0;c<C;c++) s += r[c]*r[c];
  aa[e]=s;
}

// ---------------- top-8 from precomputed Gram matrix ----------------
template<int K>
__global__ __launch_bounds__(256) void topk_feat_kernel(const float* __restrict__ G,
    const float* __restrict__ aa, int m, int* __restrict__ nbr)
{
  int b = blockIdx.y; int q = blockIdx.x*256 + threadIdx.x;
  if (q >= m) return;
  const float* Gr = G + ((size_t)b*m + q)*m;
  const float* ab = aa + (size_t)b*m;
  float aq = ab[q];
  float kd[K]; int ki[K];
  #pragma unroll
  for (int k=0;k<K;k++){ kd[k]=1e30f; ki[k]=0x7fffffff; }
  float wd = 1e30f; int wslot = 0, wi = 0x7fffffff;
  for (int j=0;j<m;j++){
    float d = aq + ab[j] - 2.0f*Gr[j];
    if (d < wd) {
      #pragma unroll
      for (int k=0;k<K;k++) if (k==wslot){ kd[k]=d; ki[k]=j; }
      wd=-1e38f; wi=-1;
      #pragma unroll
      for (int k=0;k<K;k++){
        bool g = (kd[k] > wd) || (kd[k]==wd && ki[k] > wi);
        if (g){ wd=kd[k]; wi=ki[k]; wslot=k; }
      }
    }
  }
  #pragma unroll
  for (int a=0;a<K-1;a++)
    #pragma unroll
    for (int c=0;c<K-1-a;c++) {
      bool sw = (kd[c] > kd[c+1]) || (kd[c]==kd[c+1] && ki[c] > ki[c+1]);
      if (sw) { float td=kd[c]; kd[c]=kd[c+1]; kd[c+1]=td;
                int ti=ki[c]; ki[c]=ki[c+1]; ki[c+1]=ti; }
    }
  int* o = nbr + ((size_t)b*m + q)*K;
  #pragma unroll
  for (int k=0;k<K;k++) o[k] = ki[k];
}

// ---------------- head: mean -> fc1 -> bn(batch) -> gelu -> fc2 + b ----------------
__global__ __launch_bounds__(1024) void head_kernel(const float* __restrict__ h,
    const float* __restrict__ w1, const float* __restrict__ w2,
    const float* __restrict__ b2, float* __restrict__ out)
{
  __shared__ __align__(16) float g[4*512];
  __shared__ __align__(16) float t[4*256];
  int tid = threadIdx.x;
  for (int e=tid; e<2048; e+=1024){
    int b=e>>9, c=e&511;
    float s=0;
    for (int p=0;p<16;p++) s += h[((size_t)(b*16+p))*512 + c];
    g[e] = s * (1.0f/16.0f);
  }
  __syncthreads();
  {
    int b = tid>>8, j = tid&255;
    const float4* gr = (const float4*)(g + b*512);
    const float4* wr = (const float4*)(w1 + (size_t)j*512);
    float s=0;
    for (int c=0;c<128;c++){
      float4 a=gr[c], w=wr[c];
      s = fmaf(a.x,w.x, fmaf(a.y,w.y, fmaf(a.z,w.z, fmaf(a.w,w.w, s))));
    }
    t[tid] = s;
  }
  __syncthreads();
  if (tid < 256){
    float v0=t[tid], v1=t[256+tid], v2=t[512+tid], v3=t[768+tid];
    float mu = ((v0+v1)+v2+v3)*0.25f;
    float d0=v0-mu, d1=v1-mu, d2=v2-mu, d3=v3-mu;
    float var = ((d0*d0+d1*d1)+d2*d2+d3*d3)*0.25f;
    float sq = sqrtf(var + 1e-5f);
    t[tid]     = gelu_f(d0/sq);
    t[256+tid] = gelu_f(d1/sq);
    t[512+tid] = gelu_f(d2/sq);
    t[768+tid] = gelu_f(d3/sq);
  }
  __syncthreads();
  if (tid < 160){
    int b = tid/40, o = tid%40;
    const float* tr = t + b*256; const float* wr = w2 + (size_t)o*256;
    float s=0;
    for (int j=0;j<256;j++) s = fmaf(tr[j], wr[j], s);
    out[tid] = s + b2[o];
  }
}

// =====================================================================
extern "C" void kernel_launch(void* const* d_in, const int* in_sizes, int n_in,
                              void* d_out, int out_size, void* d_ws, size_t ws_size,
                              hipStream_t stream)
{
  const float* x    = (const float*)d_in[0];
  const float* xyz  = (const float*)d_in[1];
  const float* mlpw = (const float*)d_in[2];
  const float* mlpb = (const float*)d_in[3];
  const float* c0l1 = (const float*)d_in[4];
  const float* c0l2 = (const float*)d_in[5];
  const float* L1[4] = {(const float*)d_in[6], (const float*)d_in[8],
                        (const float*)d_in[11], (const float*)d_in[14]};
  const float* L2[4] = {(const float*)d_in[7], (const float*)d_in[9],
                        (const float*)d_in[12], (const float*)d_in[15]};
  const float* SC[4] = {nullptr, (const float*)d_in[10],
                        (const float*)d_in[13], (const float*)d_in[16]};
  const float* hw1 = (const float*)d_in[17];
  const float* hw2 = (const float*)d_in[18];
  const float* hb2 = (const float*)d_in[19];
  float* out = (float*)d_out;

  float* ws = (float*)d_ws;
  const size_t MF = 1024*1024;
  float* D    = ws;               // 4M floats (pdist Gram)
  float* hA   = ws + 4*MF;
  float* hX   = ws + 5*MF;
  float* hP   = ws + 6*MF;
  float* hCT  = ws + 7*MF;
  float* hSH  = ws + 8*MF;
  float* hH1  = ws + 9*MF;
  float* hOUT = ws + 10*MF;
  int*   nbr0 = (int*)(ws + 11*MF);
  int*   nbrS = (int*)(ws + 11*MF + 400000);
  int*   nbrF = (int*)(ws + 11*MF + 450000);
  int*   sind = (int*)(ws + 11*MF + 500000);
  float* aa   = ws + 11*MF + 520000;
  float* cur1 = ws + 11*MF + 540000;
  float* cur2 = ws + 11*MF + 600000;
  float* stats= ws + 11*MF + 660000;   // 12 slots * 1024 floats
  float* part = ws + 11*MF + 680000;   // 2*NCHUNK*1024 floats scratch

  // knn on xyz, k=16
  knn3_kernel<16><<<dim3(16,4),256,0,stream>>>(xyz, 4096, xyz, nullptr, 4096, nbr0);

  auto bnstats = [&](const float* buf, int R, int O, float* slot){
    stats_part_kernel<<<NCHUNK, O, 0, stream>>>(buf, R, O, part);
    stats_final_kernel<<<1, O, 0, stream>>>(part, slot);
  };

  // initial MLP + BN + gelu
  int tot0 = 4*4096*64;
  mlp_kernel<<<(tot0+255)/256,256,0,stream>>>(x, mlpw, mlpb, hA, 4096, tot0);
  bnstats(hA, 16384, 64, stats+0*1024);
  bngelu_kernel<<<(tot0+255)/256,256,0,stream>>>(hA, stats+0*1024, 1.0f/16384.0f, 64, tot0);

  auto edgeconv = [&](const float* xin, const int* nbr, int K, int n, int Cin, int O1, int O2,
                      const float* l1, const float* l2, const float* sc,
                      int slot1, int slot2, float* outbuf)
  {
    int R = 4*n;
    dim3 gg1((O1+63)/64, (R+63)/64, 1);
    gemm_nt<true><<<gg1,256,0,stream>>>(xin, l1, hP, hCT, R, O1, Cin, Cin, 2*Cin, O1, Cin, 0,0,0);
    int t1 = R*O1;
    gathermax_kernel<<<(t1+255)/256,256,0,stream>>>(hP, nbr, hCT, nullptr, hH1, n, n, O1, K, t1);
    bnstats(hH1, R, O1, stats+(size_t)slot1*1024);
    bngelu_kernel<<<(t1+255)/256,256,0,stream>>>(hH1, stats+(size_t)slot1*1024, 1.0f/R, O1, t1);

    dim3 gg2((O2+63)/64, (R+63)/64, 1);
    gemm_nt<true><<<gg2,256,0,stream>>>(hH1, l2, hP, hCT, R, O2, O1, O1, 2*O1, O2, O1, 0,0,0);
    const float* addB;
    if (sc) {
      gemm_nt<false><<<gg2,256,0,stream>>>(xin, sc, hSH, nullptr, R, O2, Cin, Cin, Cin, O2, 0, 0,0,0);
      addB = hSH;
    } else addB = xin;
    int t2 = R*O2;
    gathermax_kernel<<<(t2+255)/256,256,0,stream>>>(hP, nbr, hCT, addB, outbuf, n, n, O2, K, t2);
    bnstats(outbuf, R, O2, stats+(size_t)slot2*1024);
    bngelu_kernel<<<(t2+255)/256,256,0,stream>>>(outbuf, stats+(size_t)slot2*1024, 1.0f/R, O2, t2);
  };

  // first edge conv (uses xyz-kNN), x = hA
  edgeconv(hA, nbr0, 16, 4096, 64, 64, 64, c0l1, c0l2, nullptr, 1, 2, hOUT);
  float* hcur = hOUT;

  const float* cur = xyz; int nprev = 4096;
  int NPTSa[4] = {1024,256,64,16};
  int CinA[4] = {64,64,128,256}, O1A[4]={64,128,256,512}, O2A[4]={64,128,256,512};
  float* curbuf[2] = {cur1, cur2};

  for (int s=0;s<4;s++){
    int m = NPTSa[s];
    // FPS
    if (nprev==4096)      fps_kernel<8,512><<<4,512,0,stream>>>(cur, nprev, m, sind);
    else if (nprev==1024) fps_kernel<2,512><<<4,512,0,stream>>>(cur, nprev, m, sind);
    else if (nprev==256)  fps_kernel<1,256><<<4,256,0,stream>>>(cur, nprev, m, sind);
    else                  fps_kernel<1,64><<<4,64,0,stream>>>(cur, nprev, m, sind);
    // kNN of sampled points against all prev points, k=8
    dim3 gk((m+255)/256, 4);
    knn3_kernel<8><<<gk,256,0,stream>>>(cur, nprev, cur, sind, m, nbrS);
    // xyz downsample (mean of 8 nbrs)
    int tc = 4*3*m;
    cur_mean_kernel<<<(tc+255)/256,256,0,stream>>>(cur, nbrS, curbuf[s&1], nprev, m, tc);
    // feature downsample (max of 8 nbrs)
    int th = 4*m*CinA[s];
    gathermax_kernel<<<(th+255)/256,256,0,stream>>>(hcur, nbrS, nullptr, nullptr, hX, m, nprev, CinA[s], 8, th);
    // feature-space kNN: norms + Gram + top-8
    norms_kernel<<<(4*m+255)/256,256,0,stream>>>(hX, aa, CinA[s], 4*m);
    dim3 gp((m+63)/64, (m+63)/64, 4);
    gemm_nt<false><<<gp,256,0,stream>>>(hX, hX, D, nullptr, m, m, CinA[s],
                                        CinA[s], CinA[s], m, 0,
                                        (long)m*CinA[s], (long)m*CinA[s], (long)m*m);
    topk_feat_kernel<8><<<gk,256,0,stream>>>(D, aa, m, nbrF);
    // edge conv
    float* outbuf = (s&1) ? hOUT : hA;
    edgeconv(hX, nbrF, 8, m, CinA[s], O1A[s], O2A[s], L1[s], L2[s], SC[s],
             3+2*s, 4+2*s, outbuf);
    hcur = outbuf;
    cur = curbuf[s&1]; nprev = m;
  }

  head_kernel<<<1,1024,0,stream>>>(hcur, hw1, hw2, hb2, out);
}

// Round 3
// 5310.049 us; speedup vs baseline: 1.4165x; 1.4165x over previous
//
#include <hip/hip_runtime.h>
#include <math.h>

#define NCHUNK 32

__device__ __forceinline__ float gelu_f(float v){
  return 0.5f*v*(1.0f+erff(v*0.70710678118654752440f));
}

// ============ chunked kNN in 3D: per-chunk top-K partials ============
template<int K>
__global__ __launch_bounds__(256) void knn3_part(
    const float* __restrict__ cand, int n, int cn,
    const float* __restrict__ qsrc, const int* __restrict__ qidx, int m,
    float* __restrict__ pd, int* __restrict__ pi, int nch)
{
  __shared__ float cx[512], cy[512], cz[512], cbb[512];
  int b = blockIdx.z, ch = blockIdx.y, c0 = ch*cn;
  const float* cb = cand + (size_t)b*3*n;
  for (int j=threadIdx.x; j<cn; j+=256) {
    float x = cb[c0+j], y = cb[n+c0+j], z = cb[2*n+c0+j];
    cx[j]=x; cy[j]=y; cz[j]=z; cbb[j]=(x*x+y*y)+z*z;
  }
  __syncthreads();
  int q = blockIdx.x*256 + threadIdx.x;
  if (q >= m) return;
  int qi = qidx ? qidx[(size_t)b*m + q] : q;
  const float* qb = qsrc + (size_t)b*3*n;
  float qx = qb[qi], qy = qb[n+qi], qz = qb[2*n+qi];
  float aa = (qx*qx + qy*qy) + qz*qz;
  float kd[K]; int ki[K];
  #pragma unroll
  for (int k=0;k<K;k++){ kd[k]=1e30f; ki[k]=0x7fffffff; }
  float wd = 1e30f; int wslot = 0, wi = 0x7fffffff;
  for (int j=0;j<cn;j++) {
    float d = aa + cbb[j] - 2.0f*((qx*cx[j]+qy*cy[j])+qz*cz[j]);
    if (d < wd) {
      int jj = c0+j;
      #pragma unroll
      for (int k=0;k<K;k++) if (k==wslot){ kd[k]=d; ki[k]=jj; }
      wd=-1e38f; wi=-1;
      #pragma unroll
      for (int k=0;k<K;k++){
        bool g = (kd[k] > wd) || (kd[k]==wd && ki[k] > wi);
        if (g){ wd=kd[k]; wi=ki[k]; wslot=k; }
      }
    }
  }
  // sort ascending (d, idx)
  #pragma unroll
  for (int a=0;a<K-1;a++)
    #pragma unroll
    for (int c=0;c<K-1-a;c++) {
      bool sw = (kd[c] > kd[c+1]) || (kd[c]==kd[c+1] && ki[c] > ki[c+1]);
      if (sw) { float td=kd[c]; kd[c]=kd[c+1]; kd[c+1]=td;
                int ti=ki[c]; ki[c]=ki[c+1]; ki[c+1]=ti; }
    }
  size_t base = (((size_t)b*m + q)*nch + ch)*K;
  #pragma unroll
  for (int k=0;k<K;k++){ pd[base+k]=kd[k]; pi[base+k]=ki[k]; }
}

// ============ merge per-chunk sorted partial lists -> final top-K ============
template<int K>
__global__ __launch_bounds__(256) void knn_merge(
    const float* __restrict__ pd, const int* __restrict__ pi,
    int nch, int total, int* __restrict__ nbr)
{
  int t = blockIdx.x*256 + threadIdx.x;
  if (t >= total) return;
  const float* pdt = pd + (size_t)t*nch*K;
  const int*   pit = pi + (size_t)t*nch*K;
  float kd[K]; int ki[K];
  #pragma unroll
  for (int k=0;k<K;k++){ kd[k]=1e30f; ki[k]=0x7fffffff; }
  float wd = 1e30f; int wslot = 0, wi = 0x7fffffff;
  int tot = nch*K;
  for (int c=0;c<tot;c++) {
    float d = pdt[c];
    if (d < wd) {
      int jj = pit[c];
      #pragma unroll
      for (int k=0;k<K;k++) if (k==wslot){ kd[k]=d; ki[k]=jj; }
      wd=-1e38f; wi=-1;
      #pragma unroll
      for (int k=0;k<K;k++){
        bool g = (kd[k] > wd) || (kd[k]==wd && ki[k] > wi);
        if (g){ wd=kd[k]; wi=ki[k]; wslot=k; }
      }
    }
  }
  #pragma unroll
  for (int a=0;a<K-1;a++)
    #pragma unroll
    for (int c=0;c<K-1-a;c++) {
      bool sw = (kd[c] > kd[c+1]) || (kd[c]==kd[c+1] && ki[c] > ki[c+1]);
      if (sw) { float td=kd[c]; kd[c]=kd[c+1]; kd[c+1]=td;
                int ti=ki[c]; ki[c]=ki[c+1]; ki[c+1]=ti; }
    }
  int* o = nbr + (size_t)t*K;
  #pragma unroll
  for (int k=0;k<K;k++) o[k] = ki[k];
}

// ============ chunked top-K from Gram (transposed, coalesced reads) ============
template<int K>
__global__ __launch_bounds__(256) void topk_part(
    const float* __restrict__ G, const float* __restrict__ aa, int m, int cn,
    float* __restrict__ pd, int* __restrict__ pi, int nch)
{
  __shared__ float abs_s[512];
  int b = blockIdx.z, ch = blockIdx.y, c0 = ch*cn;
  const float* ab = aa + (size_t)b*m;
  for (int j=threadIdx.x; j<cn; j+=256) abs_s[j] = ab[c0+j];
  __syncthreads();
  int q = blockIdx.x*256 + threadIdx.x;
  if (q >= m) return;
  float aq = ab[q];
  const float* Gq = G + (size_t)b*m*m + q;   // G symmetric bitwise -> read column
  float kd[K]; int ki[K];
  #pragma unroll
  for (int k=0;k<K;k++){ kd[k]=1e30f; ki[k]=0x7fffffff; }
  float wd = 1e30f; int wslot = 0, wi = 0x7fffffff;
  for (int j=0;j<cn;j++) {
    float g = Gq[(size_t)(c0+j)*m];
    float d = aq + abs_s[j] - 2.0f*g;
    if (d < wd) {
      int jj = c0+j;
      #pragma unroll
      for (int k=0;k<K;k++) if (k==wslot){ kd[k]=d; ki[k]=jj; }
      wd=-1e38f; wi=-1;
      #pragma unroll
      for (int k=0;k<K;k++){
        bool g2 = (kd[k] > wd) || (kd[k]==wd && ki[k] > wi);
        if (g2){ wd=kd[k]; wi=ki[k]; wslot=k; }
      }
    }
  }
  #pragma unroll
  for (int a=0;a<K-1;a++)
    #pragma unroll
    for (int c=0;c<K-1-a;c++) {
      bool sw = (kd[c] > kd[c+1]) || (kd[c]==kd[c+1] && ki[c] > ki[c+1]);
      if (sw) { float td=kd[c]; kd[c]=kd[c+1]; kd[c+1]=td;
                int ti=ki[c]; ki[c]=ki[c+1]; ki[c+1]=ti; }
    }
  size_t base = (((size_t)b*m + q)*nch + ch)*K;
  #pragma unroll
  for (int k=0;k<K;k++){ pd[base+k]=kd[k]; pi[base+k]=ki[k]; }
}

// ============ single-wave barrier-free FPS ============
template<int NP, int M>
__global__ __launch_bounds__(64,1) void fps_wave(const float* __restrict__ cur, int n,
                                                 int* __restrict__ sind)
{
  int b = blockIdx.x, lane = threadIdx.x;
  const float* cb = cur + (size_t)b*3*n;
  __shared__ float4 lp[NP*64];
  float px[NP], py[NP], pz[NP], dmin[NP];
  #pragma unroll
  for (int s=0;s<NP;s++){
    int j = lane + s*64;
    px[s]=cb[j]; py[s]=cb[n+j]; pz[s]=cb[2*n+j]; dmin[s]=1e30f;
    lp[j] = make_float4(px[s],py[s],pz[s],0.f);
  }
  __syncthreads();
  float X = lp[0].x, Y = lp[0].y, Z = lp[0].z;
  if (lane==0) sind[(size_t)b*M] = 0;
  for (int step=1; step<M; step++){
    float bv = -1e38f; int bi = 0;
    #pragma unroll
    for (int s=0;s<NP;s++){
      float dx=px[s]-X, dy=py[s]-Y, dz=pz[s]-Z;
      float d = (dx*dx + dy*dy) + dz*dz;
      float nd = fminf(dmin[s], d);
      dmin[s] = nd;
      int j = lane + s*64;
      if (nd > bv){ bv=nd; bi=j; }
    }
    #pragma unroll
    for (int off=32; off>=1; off>>=1){
      float ov = __shfl_xor(bv, off);
      int   oi = __shfl_xor(bi, off);
      if (ov > bv || (ov==bv && oi < bi)){ bv=ov; bi=oi; }
    }
    if (lane==0) sind[(size_t)b*M + step] = bi;
    float4 w = lp[bi];
    X=w.x; Y=w.y; Z=w.z;
  }
}

// ---------------- tiled NT GEMM: out[r,o] = sum_f A[r,f]*Bval(o,f) ----------------
template<bool DUAL>
__global__ __launch_bounds__(256) void gemm_nt(
    const float* __restrict__ A, const float* __restrict__ B,
    float* __restrict__ out0, float* __restrict__ out1,
    int M, int N, int Kd, int lda, int ldb, int ldo, int boff,
    long sA, long sB, long sO)
{
  int bz = blockIdx.z;
  A += (size_t)bz * sA; B += (size_t)bz * sB;
  float* o0 = out0 + (size_t)bz * sO;
  float* o1 = DUAL ? (out1 + (size_t)bz * sO) : nullptr;
  int rowBase = blockIdx.y*64, colBase = blockIdx.x*64;
  __shared__ float As[16][64], Bs0[16][64];
  __shared__ float Bs1[DUAL?16:1][64];
  int tid = threadIdx.x;
  int ty = tid>>4, tx = tid&15;
  float acc0[4][4] = {}, acc1[4][4] = {};
  int lr = tid>>2, lk = (tid&3)*4;
  for (int k0=0; k0<Kd; k0+=16) {
    float4 va = make_float4(0,0,0,0);
    int r = rowBase + lr;
    if (r < M) va = *(const float4*)(A + (size_t)r*lda + k0 + lk);
    As[lk+0][lr]=va.x; As[lk+1][lr]=va.y; As[lk+2][lr]=va.z; As[lk+3][lr]=va.w;
    float4 vb = make_float4(0,0,0,0), vb2 = make_float4(0,0,0,0);
    int c = colBase + lr;
    if (c < N) {
      vb = *(const float4*)(B + (size_t)c*ldb + k0 + lk);
      if (DUAL) vb2 = *(const float4*)(B + (size_t)c*ldb + boff + k0 + lk);
    }
    Bs0[lk+0][lr]=vb.x; Bs0[lk+1][lr]=vb.y; Bs0[lk+2][lr]=vb.z; Bs0[lk+3][lr]=vb.w;
    if (DUAL) {
      Bs1[lk+0][lr]=vb2.x-vb.x; Bs1[lk+1][lr]=vb2.y-vb.y;
      Bs1[lk+2][lr]=vb2.z-vb.z; Bs1[lk+3][lr]=vb2.w-vb.w;
    }
    __syncthreads();
    #pragma unroll
    for (int kk=0;kk<16;kk++){
      float4 a  = *(const float4*)&As[kk][ty*4];
      float4 b0 = *(const float4*)&Bs0[kk][tx*4];
      float av[4]={a.x,a.y,a.z,a.w};
      float b0v[4]={b0.x,b0.y,b0.z,b0.w};
      #pragma unroll
      for (int i=0;i<4;i++)
        #pragma unroll
        for (int j=0;j<4;j++) acc0[i][j] = fmaf(av[i], b0v[j], acc0[i][j]);
      if (DUAL) {
        float4 b1 = *(const float4*)&Bs1[kk][tx*4];
        float b1v[4]={b1.x,b1.y,b1.z,b1.w};
        #pragma unroll
        for (int i=0;i<4;i++)
          #pragma unroll
          for (int j=0;j<4;j++) acc1[i][j] = fmaf(av[i], b1v[j], acc1[i][j]);
      }
    }
    __syncthreads();
  }
  #pragma unroll
  for (int i=0;i<4;i++){
    int r = rowBase + ty*4 + i;
    if (r < M) {
      #pragma unroll
      for (int j=0;j<4;j++){
        int c = colBase + tx*4 + j;
        if (c < N) {
          o0[(size_t)r*ldo + c] = acc0[i][j];
          if (DUAL) o1[(size_t)r*ldo + c] = acc1[i][j];
        }
      }
    }
  }
}

// ---------------- gather + max over K neighbors (+ optional adds) ----------------
__global__ __launch_bounds__(256) void gathermax_kernel(
    const float* __restrict__ P, const int* __restrict__ nbr,
    const float* __restrict__ addA, const float* __restrict__ addB,
    float* __restrict__ out, int n_out, int n_src, int O, int K, int total)
{
  int e = blockIdx.x*256 + threadIdx.x;
  if (e >= total) return;
  int o = e % O; int r = e / O;
  int b = r / n_out; int i = r % n_out;
  const int* nb = nbr + ((size_t)b*n_out + i)*K;
  float mx = -1e38f;
  for (int k=0;k<K;k++){
    int j = nb[k];
    float v = P[((size_t)b*n_src + j)*O + o];
    mx = fmaxf(mx, v);
  }
  float res = mx;
  if (addA) res += addA[e];
  if (addB) res = addB[e] + res;
  out[e] = res;
}

// ---------------- deterministic per-channel stats ----------------
__global__ void stats_part_kernel(const float* __restrict__ x, int R, int O,
                                  float* __restrict__ part)
{
  int o = threadIdx.x;
  int chunk = blockIdx.x;
  int per = (R + NCHUNK - 1)/NCHUNK;
  int r0 = chunk*per, r1 = min(r0+per, R);
  float s=0, q=0;
  for (int r=r0; r<r1; r++){ float v = x[(size_t)r*O + o]; s+=v; q+=v*v; }
  part[(size_t)chunk*1024 + o] = s;
  part[(size_t)(NCHUNK+chunk)*1024 + o] = q;
}

__global__ void stats_final_kernel(const float* __restrict__ part, float* __restrict__ st)
{
  int o = threadIdx.x;
  float s=0, q=0;
  #pragma unroll 4
  for (int c=0;c<NCHUNK;c++){
    s += part[(size_t)c*1024 + o];
    q += part[(size_t)(NCHUNK+c)*1024 + o];
  }
  st[o] = s; st[512+o] = q;
}

__global__ __launch_bounds__(256) void bngelu_kernel(float* __restrict__ x,
    const float* __restrict__ st, float invR, int O, int total)
{
  int e = blockIdx.x*256 + threadIdx.x;
  if (e >= total) return;
  int o = e % O;
  float mu = st[o]*invR;
  float var = st[512+o]*invR - mu*mu;
  float v = (x[e]-mu) / sqrtf(var + 1e-5f);
  x[e] = gelu_f(v);
}

// ---------------- initial 3->64 MLP ----------------
__global__ __launch_bounds__(256) void mlp_kernel(const float* __restrict__ x,
    const float* __restrict__ w, const float* __restrict__ bias,
    float* __restrict__ out, int N, int total)
{
  int e = blockIdx.x*256 + threadIdx.x;
  if (e >= total) return;
  int o = e & 63; int r = e >> 6;
  int b = r / N; int i = r % N;
  const float* xb = x + (size_t)b*3*N;
  float v = ((w[o*3+0]*xb[i] + w[o*3+1]*xb[N+i]) + w[o*3+2]*xb[2*N+i]) + bias[o];
  out[e] = v;
}

// ---------------- mean over 8 neighbors for xyz downsample ----------------
__global__ __launch_bounds__(256) void cur_mean_kernel(const float* __restrict__ cur,
    const int* __restrict__ nbr, float* __restrict__ outc, int n, int m, int total)
{
  int e = blockIdx.x*256 + threadIdx.x;
  if (e >= total) return;
  int i = e % m; int d = (e/m)%3; int b = e/(3*m);
  const int* nb = nbr + ((size_t)b*m + i)*8;
  const float* cb = cur + (size_t)b*3*n + (size_t)d*n;
  float s=0;
  #pragma unroll
  for (int k=0;k<8;k++) s += cb[nb[k]];
  outc[(size_t)b*3*m + (size_t)d*m + i] = s * 0.125f;
}

// ---------------- per-point squared norms ----------------
__global__ __launch_bounds__(256) void norms_kernel(const float* __restrict__ h,
    float* __restrict__ aa, int C, int total)
{
  int e = blockIdx.x*256 + threadIdx.x;
  if (e >= total) return;
  const float* r = h + (size_t)e*C;
  float s=0;
  for (int c=0;c<C;c++) s += r[c]*r[c];
  aa[e]=s;
}

// ---------------- head ----------------
__global__ __launch_bounds__(1024) void head_kernel(const float* __restrict__ h,
    const float* __restrict__ w1, const float* __restrict__ w2,
    const float* __restrict__ b2, float* __restrict__ out)
{
  __shared__ __align__(16) float g[4*512];
  __shared__ __align__(16) float t[4*256];
  int tid = threadIdx.x;
  for (int e=tid; e<2048; e+=1024){
    int b=e>>9, c=e&511;
    float s=0;
    for (int p=0;p<16;p++) s += h[((size_t)(b*16+p))*512 + c];
    g[e] = s * (1.0f/16.0f);
  }
  __syncthreads();
  {
    int b = tid>>8, j = tid&255;
    const float4* gr = (const float4*)(g + b*512);
    const float4* wr = (const float4*)(w1 + (size_t)j*512);
    float s=0;
    for (int c=0;c<128;c++){
      float4 a=gr[c], w=wr[c];
      s = fmaf(a.x,w.x, fmaf(a.y,w.y, fmaf(a.z,w.z, fmaf(a.w,w.w, s))));
    }
    t[tid] = s;
  }
  __syncthreads();
  if (tid < 256){
    float v0=t[tid], v1=t[256+tid], v2=t[512+tid], v3=t[768+tid];
    float mu = ((v0+v1)+v2+v3)*0.25f;
    float d0=v0-mu, d1=v1-mu, d2=v2-mu, d3=v3-mu;
    float var = ((d0*d0+d1*d1)+d2*d2+d3*d3)*0.25f;
    float sq = sqrtf(var + 1e-5f);
    t[tid]     = gelu_f(d0/sq);
    t[256+tid] = gelu_f(d1/sq);
    t[512+tid] = gelu_f(d2/sq);
    t[768+tid] = gelu_f(d3/sq);
  }
  __syncthreads();
  if (tid < 160){
    int b = tid/40, o = tid%40;
    const float* tr = t + b*256; const float* wr = w2 + (size_t)o*256;
    float s=0;
    for (int j=0;j<256;j++) s = fmaf(tr[j], wr[j], s);
    out[tid] = s + b2[o];
  }
}

// =====================================================================
extern "C" void kernel_launch(void* const* d_in, const int* in_sizes, int n_in,
                              void* d_out, int out_size, void* d_ws, size_t ws_size,
                              hipStream_t stream)
{
  const float* x    = (const float*)d_in[0];
  const float* xyz  = (const float*)d_in[1];
  const float* mlpw = (const float*)d_in[2];
  const float* mlpb = (const float*)d_in[3];
  const float* c0l1 = (const float*)d_in[4];
  const float* c0l2 = (const float*)d_in[5];
  const float* L1[4] = {(const float*)d_in[6], (const float*)d_in[8],
                        (const float*)d_in[11], (const float*)d_in[14]};
  const float* L2[4] = {(const float*)d_in[7], (const float*)d_in[9],
                        (const float*)d_in[12], (const float*)d_in[15]};
  const float* SC[4] = {nullptr, (const float*)d_in[10],
                        (const float*)d_in[13], (const float*)d_in[16]};
  const float* hw1 = (const float*)d_in[17];
  const float* hw2 = (const float*)d_in[18];
  const float* hb2 = (const float*)d_in[19];
  float* out = (float*)d_out;

  float* ws = (float*)d_ws;
  const size_t MF = 1024*1024;
  float* D    = ws;               // 4M floats (pdist Gram)
  float* hA   = ws + 4*MF;
  float* hX   = ws + 5*MF;
  float* hP   = ws + 6*MF;
  float* hCT  = ws + 7*MF;
  float* hSH  = ws + 8*MF;
  float* hH1  = ws + 9*MF;
  float* hOUT = ws + 10*MF;
  int*   nbr0 = (int*)(ws + 11*MF);
  int*   nbrS = (int*)(ws + 11*MF + 400000);
  int*   nbrF = (int*)(ws + 11*MF + 450000);
  int*   sind = (int*)(ws + 11*MF + 500000);
  float* aa   = ws + 11*MF + 520000;
  float* cur1 = ws + 11*MF + 540000;
  float* cur2 = ws + 11*MF + 600000;
  float* stats= ws + 11*MF + 660000;   // 12 slots * 1024 floats
  float* part = ws + 11*MF + 680000;   // 2*NCHUNK*1024 floats scratch

  // transient partial-topk buffers aliasing free conv scratch:
  float* pd16 = ws + 6*MF;            // 2M floats  (hP+hCT, free pre-conv)
  int*   pi16 = (int*)(ws + 8*MF);    // 2M ints    (hSH+hH1, free pre-conv)
  float* pdS  = ws + 6*MF;            // <=1M floats (hP)
  int*   piS  = (int*)(ws + 7*MF);    // <=1M ints   (hCT)

  // ---- kNN on xyz, k=16, chunked (8 chunks of 512) + merge ----
  knn3_part<16><<<dim3(16,8,4),256,0,stream>>>(xyz, 4096, 512, xyz, nullptr, 4096,
                                               pd16, pi16, 8);
  knn_merge<16><<<(4*4096+255)/256,256,0,stream>>>(pd16, pi16, 8, 4*4096, nbr0);

  auto bnstats = [&](const float* buf, int R, int O, float* slot){
    stats_part_kernel<<<NCHUNK, O, 0, stream>>>(buf, R, O, part);
    stats_final_kernel<<<1, O, 0, stream>>>(part, slot);
  };

  // initial MLP + BN + gelu
  int tot0 = 4*4096*64;
  mlp_kernel<<<(tot0+255)/256,256,0,stream>>>(x, mlpw, mlpb, hA, 4096, tot0);
  bnstats(hA, 16384, 64, stats+0*1024);
  bngelu_kernel<<<(tot0+255)/256,256,0,stream>>>(hA, stats+0*1024, 1.0f/16384.0f, 64, tot0);

  auto edgeconv = [&](const float* xin, const int* nbr, int K, int n, int Cin, int O1, int O2,
                      const float* l1, const float* l2, const float* sc,
                      int slot1, int slot2, float* outbuf)
  {
    int R = 4*n;
    dim3 gg1((O1+63)/64, (R+63)/64, 1);
    gemm_nt<true><<<gg1,256,0,stream>>>(xin, l1, hP, hCT, R, O1, Cin, Cin, 2*Cin, O1, Cin, 0,0,0);
    int t1 = R*O1;
    gathermax_kernel<<<(t1+255)/256,256,0,stream>>>(hP, nbr, hCT, nullptr, hH1, n, n, O1, K, t1);
    bnstats(hH1, R, O1, stats+(size_t)slot1*1024);
    bngelu_kernel<<<(t1+255)/256,256,0,stream>>>(hH1, stats+(size_t)slot1*1024, 1.0f/R, O1, t1);

    dim3 gg2((O2+63)/64, (R+63)/64, 1);
    gemm_nt<true><<<gg2,256,0,stream>>>(hH1, l2, hP, hCT, R, O2, O1, O1, 2*O1, O2, O1, 0,0,0);
    const float* addB;
    if (sc) {
      gemm_nt<false><<<gg2,256,0,stream>>>(xin, sc, hSH, nullptr, R, O2, Cin, Cin, Cin, O2, 0, 0,0,0);
      addB = hSH;
    } else addB = xin;
    int t2 = R*O2;
    gathermax_kernel<<<(t2+255)/256,256,0,stream>>>(hP, nbr, hCT, addB, outbuf, n, n, O2, K, t2);
    bnstats(outbuf, R, O2, stats+(size_t)slot2*1024);
    bngelu_kernel<<<(t2+255)/256,256,0,stream>>>(outbuf, stats+(size_t)slot2*1024, 1.0f/R, O2, t2);
  };

  // first edge conv (uses xyz-kNN), x = hA
  edgeconv(hA, nbr0, 16, 4096, 64, 64, 64, c0l1, c0l2, nullptr, 1, 2, hOUT);
  float* hcur = hOUT;

  const float* cur = xyz; int nprev = 4096;
  int NPTSa[4] = {1024,256,64,16};
  int CinA[4] = {64,64,128,256}, O1A[4]={64,128,256,512}, O2A[4]={64,128,256,512};
  float* curbuf[2] = {cur1, cur2};

  for (int s=0;s<4;s++){
    int m = NPTSa[s];
    // ---- FPS: single wave per batch, no barriers ----
    if (nprev==4096)      fps_wave<64,1024><<<4,64,0,stream>>>(cur, nprev, sind);
    else if (nprev==1024) fps_wave<16,256><<<4,64,0,stream>>>(cur, nprev, sind);
    else if (nprev==256)  fps_wave<4,64><<<4,64,0,stream>>>(cur, nprev, sind);
    else                  fps_wave<1,16><<<4,64,0,stream>>>(cur, nprev, sind);
    // ---- kNN of sampled points vs all prev points, k=8, chunked ----
    int nch = (nprev>=4096) ? 8 : (nprev>=1024 ? 2 : 1);
    int cn  = nprev / nch;
    dim3 gk((m+255)/256, nch, 4);
    knn3_part<8><<<gk,256,0,stream>>>(cur, nprev, cn, cur, sind, m, pdS, piS, nch);
    knn_merge<8><<<(4*m+255)/256,256,0,stream>>>(pdS, piS, nch, 4*m, nbrS);
    // xyz downsample (mean of 8 nbrs)
    int tc = 4*3*m;
    cur_mean_kernel<<<(tc+255)/256,256,0,stream>>>(cur, nbrS, curbuf[s&1], nprev, m, tc);
    // feature downsample (max of 8 nbrs)
    int th = 4*m*CinA[s];
    gathermax_kernel<<<(th+255)/256,256,0,stream>>>(hcur, nbrS, nullptr, nullptr, hX, m, nprev, CinA[s], 8, th);
    // feature-space kNN: norms + Gram + chunked top-8
    norms_kernel<<<(4*m+255)/256,256,0,stream>>>(hX, aa, CinA[s], 4*m);
    dim3 gp((m+63)/64, (m+63)/64, 4);
    gemm_nt<false><<<gp,256,0,stream>>>(hX, hX, D, nullptr, m, m, CinA[s],
                                        CinA[s], CinA[s], m, 0,
                                        (long)m*CinA[s], (long)m*CinA[s], (long)m*m);
    int nchf = (m>=1024) ? 4 : 1;
    int cnf  = m / nchf;
    dim3 gt((m+255)/256, nchf, 4);
    topk_part<8><<<gt,256,0,stream>>>(D, aa, m, cnf, pdS, piS, nchf);
    knn_merge<8><<<(4*m+255)/256,256,0,stream>>>(pdS, piS, nchf, 4*m, nbrF);
    // edge conv
    float* outbuf = (s&1) ? hOUT : hA;
    edgeconv(hX, nbrF, 8, m, CinA[s], O1A[s], O2A[s], L1[s], L2[s], SC[s],
             3+2*s, 4+2*s, outbuf);
    hcur = outbuf;
    cur = curbuf[s&1]; nprev = m;
  }

  head_kernel<<<1,1024,0,stream>>>(hcur, hw1, hw2, hb2, out);
}

// Round 4
// 4209.418 us; speedup vs baseline: 1.7868x; 1.2615x over previous
//
#include <hip/hip_runtime.h>
#include <math.h>

#define NCHUNK 32

__device__ __forceinline__ float gelu_f(float v){
  return 0.5f*v*(1.0f+erff(v*0.70710678118654752440f));
}

// ============ chunked kNN in 3D: per-chunk top-K partials ============
template<int K>
__global__ __launch_bounds__(256) void knn3_part(
    const float* __restrict__ cand, int n, int cn,
    const float* __restrict__ qsrc, const int* __restrict__ qidx, int m,
    float* __restrict__ pd, int* __restrict__ pi, int nch)
{
  __shared__ float cx[512], cy[512], cz[512], cbb[512];
  int b = blockIdx.z, ch = blockIdx.y, c0 = ch*cn;
  const float* cb = cand + (size_t)b*3*n;
  for (int j=threadIdx.x; j<cn; j+=256) {
    float x = cb[c0+j], y = cb[n+c0+j], z = cb[2*n+c0+j];
    cx[j]=x; cy[j]=y; cz[j]=z; cbb[j]=(x*x+y*y)+z*z;
  }
  __syncthreads();
  int q = blockIdx.x*256 + threadIdx.x;
  if (q >= m) return;
  int qi = qidx ? qidx[(size_t)b*m + q] : q;
  const float* qb = qsrc + (size_t)b*3*n;
  float qx = qb[qi], qy = qb[n+qi], qz = qb[2*n+qi];
  float aa = (qx*qx + qy*qy) + qz*qz;
  float kd[K]; int ki[K];
  #pragma unroll
  for (int k=0;k<K;k++){ kd[k]=1e30f; ki[k]=0x7fffffff; }
  float wd = 1e30f; int wslot = 0, wi = 0x7fffffff;
  for (int j=0;j<cn;j++) {
    float d = aa + cbb[j] - 2.0f*((qx*cx[j]+qy*cy[j])+qz*cz[j]);
    if (d < wd) {
      int jj = c0+j;
      #pragma unroll
      for (int k=0;k<K;k++) if (k==wslot){ kd[k]=d; ki[k]=jj; }
      wd=-1e38f; wi=-1;
      #pragma unroll
      for (int k=0;k<K;k++){
        bool g = (kd[k] > wd) || (kd[k]==wd && ki[k] > wi);
        if (g){ wd=kd[k]; wi=ki[k]; wslot=k; }
      }
    }
  }
  // sort ascending (d, idx)
  #pragma unroll
  for (int a=0;a<K-1;a++)
    #pragma unroll
    for (int c=0;c<K-1-a;c++) {
      bool sw = (kd[c] > kd[c+1]) || (kd[c]==kd[c+1] && ki[c] > ki[c+1]);
      if (sw) { float td=kd[c]; kd[c]=kd[c+1]; kd[c+1]=td;
                int ti=ki[c]; ki[c]=ki[c+1]; ki[c+1]=ti; }
    }
  size_t base = (((size_t)b*m + q)*nch + ch)*K;
  #pragma unroll
  for (int k=0;k<K;k++){ pd[base+k]=kd[k]; pi[base+k]=ki[k]; }
}

// ============ merge per-chunk sorted partial lists -> final top-K ============
template<int K>
__global__ __launch_bounds__(256) void knn_merge(
    const float* __restrict__ pd, const int* __restrict__ pi,
    int nch, int total, int* __restrict__ nbr)
{
  int t = blockIdx.x*256 + threadIdx.x;
  if (t >= total) return;
  const float* pdt = pd + (size_t)t*nch*K;
  const int*   pit = pi + (size_t)t*nch*K;
  float kd[K]; int ki[K];
  #pragma unroll
  for (int k=0;k<K;k++){ kd[k]=1e30f; ki[k]=0x7fffffff; }
  float wd = 1e30f; int wslot = 0, wi = 0x7fffffff;
  int tot = nch*K;
  for (int c=0;c<tot;c++) {
    float d = pdt[c];
    if (d < wd) {
      int jj = pit[c];
      #pragma unroll
      for (int k=0;k<K;k++) if (k==wslot){ kd[k]=d; ki[k]=jj; }
      wd=-1e38f; wi=-1;
      #pragma unroll
      for (int k=0;k<K;k++){
        bool g = (kd[k] > wd) || (kd[k]==wd && ki[k] > wi);
        if (g){ wd=kd[k]; wi=ki[k]; wslot=k; }
      }
    }
  }
  #pragma unroll
  for (int a=0;a<K-1;a++)
    #pragma unroll
    for (int c=0;c<K-1-a;c++) {
      bool sw = (kd[c] > kd[c+1]) || (kd[c]==kd[c+1] && ki[c] > ki[c+1]);
      if (sw) { float td=kd[c]; kd[c]=kd[c+1]; kd[c+1]=td;
                int ti=ki[c]; ki[c]=ki[c+1]; ki[c+1]=ti; }
    }
  int* o = nbr + (size_t)t*K;
  #pragma unroll
  for (int k=0;k<K;k++) o[k] = ki[k];
}

// ============ chunked top-K from Gram (transposed, coalesced reads) ============
template<int K>
__global__ __launch_bounds__(256) void topk_part(
    const float* __restrict__ G, const float* __restrict__ aa, int m, int cn,
    float* __restrict__ pd, int* __restrict__ pi, int nch)
{
  __shared__ float abs_s[512];
  int b = blockIdx.z, ch = blockIdx.y, c0 = ch*cn;
  const float* ab = aa + (size_t)b*m;
  for (int j=threadIdx.x; j<cn; j+=256) abs_s[j] = ab[c0+j];
  __syncthreads();
  int q = blockIdx.x*256 + threadIdx.x;
  if (q >= m) return;
  float aq = ab[q];
  const float* Gq = G + (size_t)b*m*m + q;   // G symmetric bitwise -> read column
  float kd[K]; int ki[K];
  #pragma unroll
  for (int k=0;k<K;k++){ kd[k]=1e30f; ki[k]=0x7fffffff; }
  float wd = 1e30f; int wslot = 0, wi = 0x7fffffff;
  for (int j=0;j<cn;j++) {
    float g = Gq[(size_t)(c0+j)*m];
    float d = aq + abs_s[j] - 2.0f*g;
    if (d < wd) {
      int jj = c0+j;
      #pragma unroll
      for (int k=0;k<K;k++) if (k==wslot){ kd[k]=d; ki[k]=jj; }
      wd=-1e38f; wi=-1;
      #pragma unroll
      for (int k=0;k<K;k++){
        bool g2 = (kd[k] > wd) || (kd[k]==wd && ki[k] > wi);
        if (g2){ wd=kd[k]; wi=ki[k]; wslot=k; }
      }
    }
  }
  #pragma unroll
  for (int a=0;a<K-1;a++)
    #pragma unroll
    for (int c=0;c<K-1-a;c++) {
      bool sw = (kd[c] > kd[c+1]) || (kd[c]==kd[c+1] && ki[c] > ki[c+1]);
      if (sw) { float td=kd[c]; kd[c]=kd[c+1]; kd[c+1]=td;
                int ti=ki[c]; ki[c]=ki[c+1]; ki[c+1]=ti; }
    }
  size_t base = (((size_t)b*m + q)*nch + ch)*K;
  #pragma unroll
  for (int k=0;k<K;k++){ pd[base+k]=kd[k]; pi[base+k]=ki[k]; }
}

// ============ multi-wave FPS: spill-free, u64-key tree argmax, 1 barrier/step ============
// key = (d_bits << 32) | ~j : distances are >= 0 so float bits are order-monotone;
// max(key) == max d, ties -> lowest index j (jnp.argmax first-occurrence semantics).
template<int NP, int T, int M>
__global__ __launch_bounds__(T,1) void fps_mw(const float* __restrict__ cur, int n,
                                              int* __restrict__ sind)
{
  constexpr int NW = T/64;
  int b = blockIdx.x, tid = threadIdx.x;
  int wv = tid>>6;
  const float* cb = cur + (size_t)b*3*n;
  __shared__ float4 lp[NP*T];
  __shared__ unsigned long long wred[2][NW];
  float px[NP], py[NP], pz[NP], dmin[NP];
  #pragma unroll
  for (int s=0;s<NP;s++){
    int j = tid + s*T;
    px[s]=cb[j]; py[s]=cb[n+j]; pz[s]=cb[2*n+j]; dmin[s]=1e30f;
    lp[j] = make_float4(px[s],py[s],pz[s],0.f);
  }
  __syncthreads();
  float X = lp[0].x, Y = lp[0].y, Z = lp[0].z;
  if (tid==0) sind[(size_t)b*M] = 0;
  int p = 0;
  for (int step=1; step<M; step++){
    unsigned long long key[NP];
    #pragma unroll
    for (int s=0;s<NP;s++){
      float dx=px[s]-X, dy=py[s]-Y, dz=pz[s]-Z;
      float d = (dx*dx + dy*dy) + dz*dz;
      float nd = fminf(dmin[s], d);
      dmin[s] = nd;
      int j = tid + s*T;
      key[s] = ((unsigned long long)__float_as_uint(nd)<<32) | (unsigned)(~j);
    }
    // in-lane tree reduce
    #pragma unroll
    for (int w=NP; w>1; w>>=1)
      #pragma unroll
      for (int i=0;i<NP;i++) if (i < (w>>1))
        key[i] = key[i] >= key[i+(w>>1)] ? key[i] : key[i+(w>>1)];
    unsigned long long k0 = key[0];
    // wave butterfly
    #pragma unroll
    for (int off=32; off>=1; off>>=1){
      unsigned long long o = __shfl_xor(k0, off);
      k0 = k0 >= o ? k0 : o;
    }
    if ((tid&63)==0) wred[p][wv] = k0;
    __syncthreads();
    unsigned long long gk = wred[p][0];
    #pragma unroll
    for (int w=1;w<NW;w++){
      unsigned long long o = wred[p][w];
      gk = gk >= o ? gk : o;
    }
    int gi = (int)(~(unsigned)gk);
    if (tid==0) sind[(size_t)b*M + step] = gi;
    float4 wp = lp[gi];
    X=wp.x; Y=wp.y; Z=wp.z;
    p ^= 1;
  }
}

// ---------------- tiled NT GEMM: out[r,o] = sum_f A[r,f]*Bval(o,f) ----------------
template<bool DUAL>
__global__ __launch_bounds__(256) void gemm_nt(
    const float* __restrict__ A, const float* __restrict__ B,
    float* __restrict__ out0, float* __restrict__ out1,
    int M, int N, int Kd, int lda, int ldb, int ldo, int boff,
    long sA, long sB, long sO)
{
  int bz = blockIdx.z;
  A += (size_t)bz * sA; B += (size_t)bz * sB;
  float* o0 = out0 + (size_t)bz * sO;
  float* o1 = DUAL ? (out1 + (size_t)bz * sO) : nullptr;
  int rowBase = blockIdx.y*64, colBase = blockIdx.x*64;
  __shared__ float As[16][64], Bs0[16][64];
  __shared__ float Bs1[DUAL?16:1][64];
  int tid = threadIdx.x;
  int ty = tid>>4, tx = tid&15;
  float acc0[4][4] = {}, acc1[4][4] = {};
  int lr = tid>>2, lk = (tid&3)*4;
  for (int k0=0; k0<Kd; k0+=16) {
    float4 va = make_float4(0,0,0,0);
    int r = rowBase + lr;
    if (r < M) va = *(const float4*)(A + (size_t)r*lda + k0 + lk);
    As[lk+0][lr]=va.x; As[lk+1][lr]=va.y; As[lk+2][lr]=va.z; As[lk+3][lr]=va.w;
    float4 vb = make_float4(0,0,0,0), vb2 = make_float4(0,0,0,0);
    int c = colBase + lr;
    if (c < N) {
      vb = *(const float4*)(B + (size_t)c*ldb + k0 + lk);
      if (DUAL) vb2 = *(const float4*)(B + (size_t)c*ldb + boff + k0 + lk);
    }
    Bs0[lk+0][lr]=vb.x; Bs0[lk+1][lr]=vb.y; Bs0[lk+2][lr]=vb.z; Bs0[lk+3][lr]=vb.w;
    if (DUAL) {
      Bs1[lk+0][lr]=vb2.x-vb.x; Bs1[lk+1][lr]=vb2.y-vb.y;
      Bs1[lk+2][lr]=vb2.z-vb.z; Bs1[lk+3][lr]=vb2.w-vb.w;
    }
    __syncthreads();
    #pragma unroll
    for (int kk=0;kk<16;kk++){
      float4 a  = *(const float4*)&As[kk][ty*4];
      float4 b0 = *(const float4*)&Bs0[kk][tx*4];
      float av[4]={a.x,a.y,a.z,a.w};
      float b0v[4]={b0.x,b0.y,b0.z,b0.w};
      #pragma unroll
      for (int i=0;i<4;i++)
        #pragma unroll
        for (int j=0;j<4;j++) acc0[i][j] = fmaf(av[i], b0v[j], acc0[i][j]);
      if (DUAL) {
        float4 b1 = *(const float4*)&Bs1[kk][tx*4];
        float b1v[4]={b1.x,b1.y,b1.z,b1.w};
        #pragma unroll
        for (int i=0;i<4;i++)
          #pragma unroll
          for (int j=0;j<4;j++) acc1[i][j] = fmaf(av[i], b1v[j], acc1[i][j]);
      }
    }
    __syncthreads();
  }
  #pragma unroll
  for (int i=0;i<4;i++){
    int r = rowBase + ty*4 + i;
    if (r < M) {
      #pragma unroll
      for (int j=0;j<4;j++){
        int c = colBase + tx*4 + j;
        if (c < N) {
          o0[(size_t)r*ldo + c] = acc0[i][j];
          if (DUAL) o1[(size_t)r*ldo + c] = acc1[i][j];
        }
      }
    }
  }
}

// ---------------- gather + max over K neighbors (+ optional adds) ----------------
__global__ __launch_bounds__(256) void gathermax_kernel(
    const float* __restrict__ P, const int* __restrict__ nbr,
    const float* __restrict__ addA, const float* __restrict__ addB,
    float* __restrict__ out, int n_out, int n_src, int O, int K, int total)
{
  int e = blockIdx.x*256 + threadIdx.x;
  if (e >= total) return;
  int o = e % O; int r = e / O;
  int b = r / n_out; int i = r % n_out;
  const int* nb = nbr + ((size_t)b*n_out + i)*K;
  float mx = -1e38f;
  for (int k=0;k<K;k++){
    int j = nb[k];
    float v = P[((size_t)b*n_src + j)*O + o];
    mx = fmaxf(mx, v);
  }
  float res = mx;
  if (addA) res += addA[e];
  if (addB) res = addB[e] + res;
  out[e] = res;
}

// ---------------- deterministic per-channel stats ----------------
__global__ void stats_part_kernel(const float* __restrict__ x, int R, int O,
                                  float* __restrict__ part)
{
  int o = threadIdx.x;
  int chunk = blockIdx.x;
  int per = (R + NCHUNK - 1)/NCHUNK;
  int r0 = chunk*per, r1 = min(r0+per, R);
  float s=0, q=0;
  for (int r=r0; r<r1; r++){ float v = x[(size_t)r*O + o]; s+=v; q+=v*v; }
  part[(size_t)chunk*1024 + o] = s;
  part[(size_t)(NCHUNK+chunk)*1024 + o] = q;
}

__global__ void stats_final_kernel(const float* __restrict__ part, float* __restrict__ st)
{
  int o = threadIdx.x;
  float s=0, q=0;
  #pragma unroll 4
  for (int c=0;c<NCHUNK;c++){
    s += part[(size_t)c*1024 + o];
    q += part[(size_t)(NCHUNK+c)*1024 + o];
  }
  st[o] = s; st[512+o] = q;
}

__global__ __launch_bounds__(256) void bngelu_kernel(float* __restrict__ x,
    const float* __restrict__ st, float invR, int O, int total)
{
  int e = blockIdx.x*256 + threadIdx.x;
  if (e >= total) return;
  int o = e % O;
  float mu = st[o]*invR;
  float var = st[512+o]*invR - mu*mu;
  float v = (x[e]-mu) / sqrtf(var + 1e-5f);
  x[e] = gelu_f(v);
}

// ---------------- initial 3->64 MLP ----------------
__global__ __launch_bounds__(256) void mlp_kernel(const float* __restrict__ x,
    const float* __restrict__ w, const float* __restrict__ bias,
    float* __restrict__ out, int N, int total)
{
  int e = blockIdx.x*256 + threadIdx.x;
  if (e >= total) return;
  int o = e & 63; int r = e >> 6;
  int b = r / N; int i = r % N;
  const float* xb = x + (size_t)b*3*N;
  float v = ((w[o*3+0]*xb[i] + w[o*3+1]*xb[N+i]) + w[o*3+2]*xb[2*N+i]) + bias[o];
  out[e] = v;
}

// ---------------- mean over 8 neighbors for xyz downsample ----------------
__global__ __launch_bounds__(256) void cur_mean_kernel(const float* __restrict__ cur,
    const int* __restrict__ nbr, float* __restrict__ outc, int n, int m, int total)
{
  int e = blockIdx.x*256 + threadIdx.x;
  if (e >= total) return;
  int i = e % m; int d = (e/m)%3; int b = e/(3*m);
  const int* nb = nbr + ((size_t)b*m + i)*8;
  const float* cb = cur + (size_t)b*3*n + (size_t)d*n;
  float s=0;
  #pragma unroll
  for (int k=0;k<8;k++) s += cb[nb[k]];
  outc[(size_t)b*3*m + (size_t)d*m + i] = s * 0.125f;
}

// ---------------- per-point squared norms ----------------
__global__ __launch_bounds__(256) void norms_kernel(const float* __restrict__ h,
    float* __restrict__ aa, int C, int total)
{
  int e = blockIdx.x*256 + threadIdx.x;
  if (e >= total) return;
  const float* r = h + (size_t)e*C;
  float s=0;
  for (int c=0;c<C;c++) s += r[c]*r[c];
  aa[e]=s;
}

// ---------------- head ----------------
__global__ __launch_bounds__(1024) void head_kernel(const float* __restrict__ h,
    const float* __restrict__ w1, const float* __restrict__ w2,
    const float* __restrict__ b2, float* __restrict__ out)
{
  __shared__ __align__(16) float g[4*512];
  __shared__ __align__(16) float t[4*256];
  int tid = threadIdx.x;
  for (int e=tid; e<2048; e+=1024){
    int b=e>>9, c=e&511;
    float s=0;
    for (int p=0;p<16;p++) s += h[((size_t)(b*16+p))*512 + c];
    g[e] = s * (1.0f/16.0f);
  }
  __syncthreads();
  {
    int b = tid>>8, j = tid&255;
    const float4* gr = (const float4*)(g + b*512);
    const float4* wr = (const float4*)(w1 + (size_t)j*512);
    float s=0;
    for (int c=0;c<128;c++){
      float4 a=gr[c], w=wr[c];
      s = fmaf(a.x,w.x, fmaf(a.y,w.y, fmaf(a.z,w.z, fmaf(a.w,w.w, s))));
    }
    t[tid] = s;
  }
  __syncthreads();
  if (tid < 256){
    float v0=t[tid], v1=t[256+tid], v2=t[512+tid], v3=t[768+tid];
    float mu = ((v0+v1)+v2+v3)*0.25f;
    float d0=v0-mu, d1=v1-mu, d2=v2-mu, d3=v3-mu;
    float var = ((d0*d0+d1*d1)+d2*d2+d3*d3)*0.25f;
    float sq = sqrtf(var + 1e-5f);
    t[tid]     = gelu_f(d0/sq);
    t[256+tid] = gelu_f(d1/sq);
    t[512+tid] = gelu_f(d2/sq);
    t[768+tid] = gelu_f(d3/sq);
  }
  __syncthreads();
  if (tid < 160){
    int b = tid/40, o = tid%40;
    const float* tr = t + b*256; const float* wr = w2 + (size_t)o*256;
    float s=0;
    for (int j=0;j<256;j++) s = fmaf(tr[j], wr[j], s);
    out[tid] = s + b2[o];
  }
}

// =====================================================================
extern "C" void kernel_launch(void* const* d_in, const int* in_sizes, int n_in,
                              void* d_out, int out_size, void* d_ws, size_t ws_size,
                              hipStream_t stream)
{
  const float* x    = (const float*)d_in[0];
  const float* xyz  = (const float*)d_in[1];
  const float* mlpw = (const float*)d_in[2];
  const float* mlpb = (const float*)d_in[3];
  const float* c0l1 = (const float*)d_in[4];
  const float* c0l2 = (const float*)d_in[5];
  const float* L1[4] = {(const float*)d_in[6], (const float*)d_in[8],
                        (const float*)d_in[11], (const float*)d_in[14]};
  const float* L2[4] = {(const float*)d_in[7], (const float*)d_in[9],
                        (const float*)d_in[12], (const float*)d_in[15]};
  const float* SC[4] = {nullptr, (const float*)d_in[10],
                        (const float*)d_in[13], (const float*)d_in[16]};
  const float* hw1 = (const float*)d_in[17];
  const float* hw2 = (const float*)d_in[18];
  const float* hb2 = (const float*)d_in[19];
  float* out = (float*)d_out;

  float* ws = (float*)d_ws;
  const size_t MF = 1024*1024;
  float* D    = ws;               // 4M floats (pdist Gram)
  float* hA   = ws + 4*MF;
  float* hX   = ws + 5*MF;
  float* hP   = ws + 6*MF;
  float* hCT  = ws + 7*MF;
  float* hSH  = ws + 8*MF;
  float* hH1  = ws + 9*MF;
  float* hOUT = ws + 10*MF;
  int*   nbr0 = (int*)(ws + 11*MF);
  int*   nbrS = (int*)(ws + 11*MF + 400000);
  int*   nbrF = (int*)(ws + 11*MF + 450000);
  int*   sind = (int*)(ws + 11*MF + 500000);
  float* aa   = ws + 11*MF + 520000;
  float* cur1 = ws + 11*MF + 540000;
  float* cur2 = ws + 11*MF + 600000;
  float* stats= ws + 11*MF + 660000;   // 12 slots * 1024 floats
  float* part = ws + 11*MF + 680000;   // 2*NCHUNK*1024 floats scratch

  // transient partial-topk buffers aliasing free conv scratch:
  float* pd16 = ws + 6*MF;            // 2M floats  (hP+hCT, free pre-conv)
  int*   pi16 = (int*)(ws + 8*MF);    // 2M ints    (hSH+hH1, free pre-conv)
  float* pdS  = ws + 6*MF;            // <=1M floats (hP)
  int*   piS  = (int*)(ws + 7*MF);    // <=1M ints   (hCT)

  // ---- kNN on xyz, k=16, chunked (8 chunks of 512) + merge ----
  knn3_part<16><<<dim3(16,8,4),256,0,stream>>>(xyz, 4096, 512, xyz, nullptr, 4096,
                                               pd16, pi16, 8);
  knn_merge<16><<<(4*4096+255)/256,256,0,stream>>>(pd16, pi16, 8, 4*4096, nbr0);

  auto bnstats = [&](const float* buf, int R, int O, float* slot){
    stats_part_kernel<<<NCHUNK, O, 0, stream>>>(buf, R, O, part);
    stats_final_kernel<<<1, O, 0, stream>>>(part, slot);
  };

  // initial MLP + BN + gelu
  int tot0 = 4*4096*64;
  mlp_kernel<<<(tot0+255)/256,256,0,stream>>>(x, mlpw, mlpb, hA, 4096, tot0);
  bnstats(hA, 16384, 64, stats+0*1024);
  bngelu_kernel<<<(tot0+255)/256,256,0,stream>>>(hA, stats+0*1024, 1.0f/16384.0f, 64, tot0);

  auto edgeconv = [&](const float* xin, const int* nbr, int K, int n, int Cin, int O1, int O2,
                      const float* l1, const float* l2, const float* sc,
                      int slot1, int slot2, float* outbuf)
  {
    int R = 4*n;
    dim3 gg1((O1+63)/64, (R+63)/64, 1);
    gemm_nt<true><<<gg1,256,0,stream>>>(xin, l1, hP, hCT, R, O1, Cin, Cin, 2*Cin, O1, Cin, 0,0,0);
    int t1 = R*O1;
    gathermax_kernel<<<(t1+255)/256,256,0,stream>>>(hP, nbr, hCT, nullptr, hH1, n, n, O1, K, t1);
    bnstats(hH1, R, O1, stats+(size_t)slot1*1024);
    bngelu_kernel<<<(t1+255)/256,256,0,stream>>>(hH1, stats+(size_t)slot1*1024, 1.0f/R, O1, t1);

    dim3 gg2((O2+63)/64, (R+63)/64, 1);
    gemm_nt<true><<<gg2,256,0,stream>>>(hH1, l2, hP, hCT, R, O2, O1, O1, 2*O1, O2, O1, 0,0,0);
    const float* addB;
    if (sc) {
      gemm_nt<false><<<gg2,256,0,stream>>>(xin, sc, hSH, nullptr, R, O2, Cin, Cin, Cin, O2, 0, 0,0,0);
      addB = hSH;
    } else addB = xin;
    int t2 = R*O2;
    gathermax_kernel<<<(t2+255)/256,256,0,stream>>>(hP, nbr, hCT, addB, outbuf, n, n, O2, K, t2);
    bnstats(outbuf, R, O2, stats+(size_t)slot2*1024);
    bngelu_kernel<<<(t2+255)/256,256,0,stream>>>(outbuf, stats+(size_t)slot2*1024, 1.0f/R, O2, t2);
  };

  // first edge conv (uses xyz-kNN), x = hA
  edgeconv(hA, nbr0, 16, 4096, 64, 64, 64, c0l1, c0l2, nullptr, 1, 2, hOUT);
  float* hcur = hOUT;

  const float* cur = xyz; int nprev = 4096;
  int NPTSa[4] = {1024,256,64,16};
  int CinA[4] = {64,64,128,256}, O1A[4]={64,128,256,512}, O2A[4]={64,128,256,512};
  float* curbuf[2] = {cur1, cur2};

  for (int s=0;s<4;s++){
    int m = NPTSa[s];
    // ---- FPS: 4 waves, spill-free, tree argmax ----
    if (nprev==4096)      fps_mw<16,256,1024><<<4,256,0,stream>>>(cur, nprev, sind);
    else if (nprev==1024) fps_mw<4,256,256><<<4,256,0,stream>>>(cur, nprev, sind);
    else if (nprev==256)  fps_mw<1,256,64><<<4,256,0,stream>>>(cur, nprev, sind);
    else                  fps_mw<1,64,16><<<4,64,0,stream>>>(cur, nprev, sind);
    // ---- kNN of sampled points vs all prev points, k=8, chunked ----
    int nch = (nprev>=4096) ? 8 : (nprev>=1024 ? 2 : 1);
    int cn  = nprev / nch;
    dim3 gk((m+255)/256, nch, 4);
    knn3_part<8><<<gk,256,0,stream>>>(cur, nprev, cn, cur, sind, m, pdS, piS, nch);
    knn_merge<8><<<(4*m+255)/256,256,0,stream>>>(pdS, piS, nch, 4*m, nbrS);
    // xyz downsample (mean of 8 nbrs)
    int tc = 4*3*m;
    cur_mean_kernel<<<(tc+255)/256,256,0,stream>>>(cur, nbrS, curbuf[s&1], nprev, m, tc);
    // feature downsample (max of 8 nbrs)
    int th = 4*m*CinA[s];
    gathermax_kernel<<<(th+255)/256,256,0,stream>>>(hcur, nbrS, nullptr, nullptr, hX, m, nprev, CinA[s], 8, th);
    // feature-space kNN: norms + Gram + chunked top-8
    norms_kernel<<<(4*m+255)/256,256,0,stream>>>(hX, aa, CinA[s], 4*m);
    dim3 gp((m+63)/64, (m+63)/64, 4);
    gemm_nt<false><<<gp,256,0,stream>>>(hX, hX, D, nullptr, m, m, CinA[s],
                                        CinA[s], CinA[s], m, 0,
                                        (long)m*CinA[s], (long)m*CinA[s], (long)m*m);
    int nchf = (m>=1024) ? 4 : 1;
    int cnf  = m / nchf;
    dim3 gt((m+255)/256, nchf, 4);
    topk_part<8><<<gt,256,0,stream>>>(D, aa, m, cnf, pdS, piS, nchf);
    knn_merge<8><<<(4*m+255)/256,256,0,stream>>>(pdS, piS, nchf, 4*m, nbrF);
    // edge conv
    float* outbuf = (s&1) ? hOUT : hA;
    edgeconv(hX, nbrF, 8, m, CinA[s], O1A[s], O2A[s], L1[s], L2[s], SC[s],
             3+2*s, 4+2*s, outbuf);
    hcur = outbuf;
    cur = curbuf[s&1]; nprev = m;
  }

  head_kernel<<<1,1024,0,stream>>>(hcur, hw1, hw2, hb2, out);
}

// Round 5
// 2393.316 us; speedup vs baseline: 3.1427x; 1.7588x over previous
//
#include <hip/hip_runtime.h>
#include <math.h>

#define NCHUNK 32

__device__ __forceinline__ float gelu_f(float v){
  return 0.5f*v*(1.0f+erff(v*0.70710678118654752440f));
}

__device__ __forceinline__ unsigned flipf(float d){
  unsigned u = __float_as_uint(d);
  return (u & 0x80000000u) ? ~u : (u | 0x80000000u);
}

// ============ wave-per-query kNN in 3D: per-lane reg top-K + wave merge ============
// key = (flip(d)<<32) | idx ; lex order == (d asc, idx asc) == stable top_k order.
template<int K>
__global__ __launch_bounds__(256) void knn_wave(
    const float* __restrict__ cand, int n,
    const float* __restrict__ qsrc, const int* __restrict__ qidx, int m,
    int* __restrict__ nbr)
{
  __shared__ float cx[1024], cy[1024], cz[1024], cbb[1024];
  int b = blockIdx.y;
  int wv = threadIdx.x >> 6, lane = threadIdx.x & 63;
  int q = blockIdx.x*4 + wv;           // m is always a multiple of 4
  const float* cb = cand + (size_t)b*3*n;
  int qi = qidx ? qidx[(size_t)b*m + q] : q;
  const float* qb = qsrc + (size_t)b*3*n;
  float qx = qb[qi], qy = qb[n+qi], qz = qb[2*n+qi];
  float aa = (qx*qx + qy*qy) + qz*qz;

  unsigned long long a[K];
  #pragma unroll
  for (int k=0;k<K;k++) a[k] = ~0ull;
  unsigned long long worst = ~0ull; int wslot = 0;

  for (int base=0; base<n; base+=1024){
    int cnt = min(1024, n-base);
    for (int j=threadIdx.x; j<cnt; j+=256){
      float x=cb[base+j], y=cb[n+base+j], z=cb[2*n+base+j];
      cx[j]=x; cy[j]=y; cz[j]=z; cbb[j]=(x*x+y*y)+z*z;
    }
    __syncthreads();
    int steps = cnt >> 6;
    for (int i=0;i<steps;i++){
      int j = lane + (i<<6);
      float d = aa + cbb[j] - 2.0f*((qx*cx[j]+qy*cy[j])+qz*cz[j]);
      unsigned long long key = ((unsigned long long)flipf(d)<<32) | (unsigned)(base+j);
      if (key < worst){
        #pragma unroll
        for (int k=0;k<K;k++) if (k==wslot) a[k] = key;
        worst = a[0]; wslot = 0;
        #pragma unroll
        for (int k=1;k<K;k++){
          bool g = a[k] > worst;
          worst = g ? a[k] : worst;
          wslot = g ? k : wslot;
        }
      }
    }
    __syncthreads();
  }

  // per-lane bitonic sort ascending
  #pragma unroll
  for (int kk=2; kk<=K; kk<<=1)
    #pragma unroll
    for (int jj=kk>>1; jj>0; jj>>=1)
      #pragma unroll
      for (int i=0;i<K;i++){
        int l = i ^ jj;
        if (l > i){
          bool dirUp = ((i & kk) == 0);
          unsigned long long x = a[i], y = a[l];
          bool sw = dirUp ? (x > y) : (x < y);
          a[i] = sw ? y : x;
          a[l] = sw ? x : y;
        }
      }

  // K rounds of wave-min extraction with sorted-list pop
  unsigned long long head = a[0];
  int res[K];
  #pragma unroll
  for (int r=0; r<K; r++){
    unsigned long long k0 = head;
    #pragma unroll
    for (int off=32; off>=1; off>>=1){
      unsigned lo = (unsigned)k0, hi = (unsigned)(k0>>32);
      lo = __shfl_xor(lo, off); hi = __shfl_xor(hi, off);
      unsigned long long o = ((unsigned long long)hi<<32) | lo;
      k0 = o < k0 ? o : k0;
    }
    res[r] = (int)(unsigned)k0;
    if (head == k0){
      #pragma unroll
      for (int i2=0;i2<K-1;i2++) a[i2]=a[i2+1];
      a[K-1] = ~0ull;
      head = a[0];
    }
  }
  if (lane == 0){
    int* o = nbr + ((size_t)b*m + q)*K;
    #pragma unroll
    for (int r=0;r<K;r++) o[r] = res[r];
  }
}

// ============ wave-per-query top-K from Gram rows (coalesced) ============
template<int K>
__global__ __launch_bounds__(256) void topk_wave(
    const float* __restrict__ G, const float* __restrict__ aa, int m,
    int* __restrict__ nbr)
{
  __shared__ float abs_s[1024];
  int b = blockIdx.y;
  int wv = threadIdx.x >> 6, lane = threadIdx.x & 63;
  int q = blockIdx.x*4 + wv;
  const float* ab = aa + (size_t)b*m;
  for (int j=threadIdx.x; j<m; j+=256) abs_s[j] = ab[j];
  __syncthreads();
  float aq = ab[q];
  const float* Gq = G + ((size_t)b*m + q)*m;   // row; bitwise symmetric Gram

  unsigned long long a[K];
  #pragma unroll
  for (int k=0;k<K;k++) a[k] = ~0ull;
  unsigned long long worst = ~0ull; int wslot = 0;

  int steps = (m+63)>>6;
  for (int i=0;i<steps;i++){
    int j = lane + (i<<6);
    unsigned long long key = ~0ull;
    if (j < m){
      float g = Gq[j];
      float d = aq + abs_s[j] - 2.0f*g;
      key = ((unsigned long long)flipf(d)<<32) | (unsigned)j;
    }
    if (key < worst){
      #pragma unroll
      for (int k=0;k<K;k++) if (k==wslot) a[k] = key;
      worst = a[0]; wslot = 0;
      #pragma unroll
      for (int k=1;k<K;k++){
        bool g = a[k] > worst;
        worst = g ? a[k] : worst;
        wslot = g ? k : wslot;
      }
    }
  }

  #pragma unroll
  for (int kk=2; kk<=K; kk<<=1)
    #pragma unroll
    for (int jj=kk>>1; jj>0; jj>>=1)
      #pragma unroll
      for (int i=0;i<K;i++){
        int l = i ^ jj;
        if (l > i){
          bool dirUp = ((i & kk) == 0);
          unsigned long long x = a[i], y = a[l];
          bool sw = dirUp ? (x > y) : (x < y);
          a[i] = sw ? y : x;
          a[l] = sw ? x : y;
        }
      }

  unsigned long long head = a[0];
  int res[K];
  #pragma unroll
  for (int r=0; r<K; r++){
    unsigned long long k0 = head;
    #pragma unroll
    for (int off=32; off>=1; off>>=1){
      unsigned lo = (unsigned)k0, hi = (unsigned)(k0>>32);
      lo = __shfl_xor(lo, off); hi = __shfl_xor(hi, off);
      unsigned long long o = ((unsigned long long)hi<<32) | lo;
      k0 = o < k0 ? o : k0;
    }
    res[r] = (int)(unsigned)k0;
    if (head == k0){
      #pragma unroll
      for (int i2=0;i2<K-1;i2++) a[i2]=a[i2+1];
      a[K-1] = ~0ull;
      head = a[0];
    }
  }
  if (lane == 0){
    int* o = nbr + ((size_t)b*m + q)*K;
    #pragma unroll
    for (int r=0;r<K;r++) o[r] = res[r];
  }
}

// ============ multi-wave FPS: spill-free, u64-key tree argmax, 1 barrier/step ============
template<int NP, int T, int M>
__global__ __launch_bounds__(T,1) void fps_mw(const float* __restrict__ cur, int n,
                                              int* __restrict__ sind)
{
  constexpr int NW = T/64;
  int b = blockIdx.x, tid = threadIdx.x;
  int wv = tid>>6;
  const float* cb = cur + (size_t)b*3*n;
  __shared__ float4 lp[NP*T];
  __shared__ unsigned long long wred[2][NW];
  float px[NP], py[NP], pz[NP], dmin[NP];
  #pragma unroll
  for (int s=0;s<NP;s++){
    int j = tid + s*T;
    px[s]=cb[j]; py[s]=cb[n+j]; pz[s]=cb[2*n+j]; dmin[s]=1e30f;
    lp[j] = make_float4(px[s],py[s],pz[s],0.f);
  }
  __syncthreads();
  float X = lp[0].x, Y = lp[0].y, Z = lp[0].z;
  if (tid==0) sind[(size_t)b*M] = 0;
  int p = 0;
  for (int step=1; step<M; step++){
    unsigned long long key[NP];
    #pragma unroll
    for (int s=0;s<NP;s++){
      float dx=px[s]-X, dy=py[s]-Y, dz=pz[s]-Z;
      float d = (dx*dx + dy*dy) + dz*dz;
      float nd = fminf(dmin[s], d);
      dmin[s] = nd;
      int j = tid + s*T;
      key[s] = ((unsigned long long)__float_as_uint(nd)<<32) | (unsigned)(~j);
    }
    #pragma unroll
    for (int w=NP; w>1; w>>=1)
      #pragma unroll
      for (int i=0;i<NP;i++) if (i < (w>>1))
        key[i] = key[i] >= key[i+(w>>1)] ? key[i] : key[i+(w>>1)];
    unsigned long long k0 = key[0];
    #pragma unroll
    for (int off=32; off>=1; off>>=1){
      unsigned long long o = __shfl_xor(k0, off);
      k0 = k0 >= o ? k0 : o;
    }
    if ((tid&63)==0) wred[p][wv] = k0;
    __syncthreads();
    unsigned long long gk = wred[p][0];
    #pragma unroll
    for (int w=1;w<NW;w++){
      unsigned long long o = wred[p][w];
      gk = gk >= o ? gk : o;
    }
    int gi = (int)(~(unsigned)gk);
    if (tid==0) sind[(size_t)b*M + step] = gi;
    float4 wp = lp[gi];
    X=wp.x; Y=wp.y; Z=wp.z;
    p ^= 1;
  }
}

// ---------------- tiled NT GEMM ----------------
template<bool DUAL>
__global__ __launch_bounds__(256) void gemm_nt(
    const float* __restrict__ A, const float* __restrict__ B,
    float* __restrict__ out0, float* __restrict__ out1,
    int M, int N, int Kd, int lda, int ldb, int ldo, int boff,
    long sA, long sB, long sO)
{
  int bz = blockIdx.z;
  A += (size_t)bz * sA; B += (size_t)bz * sB;
  float* o0 = out0 + (size_t)bz * sO;
  float* o1 = DUAL ? (out1 + (size_t)bz * sO) : nullptr;
  int rowBase = blockIdx.y*64, colBase = blockIdx.x*64;
  __shared__ float As[16][64], Bs0[16][64];
  __shared__ float Bs1[DUAL?16:1][64];
  int tid = threadIdx.x;
  int ty = tid>>4, tx = tid&15;
  float acc0[4][4] = {}, acc1[4][4] = {};
  int lr = tid>>2, lk = (tid&3)*4;
  for (int k0=0; k0<Kd; k0+=16) {
    float4 va = make_float4(0,0,0,0);
    int r = rowBase + lr;
    if (r < M) va = *(const float4*)(A + (size_t)r*lda + k0 + lk);
    As[lk+0][lr]=va.x; As[lk+1][lr]=va.y; As[lk+2][lr]=va.z; As[lk+3][lr]=va.w;
    float4 vb = make_float4(0,0,0,0), vb2 = make_float4(0,0,0,0);
    int c = colBase + lr;
    if (c < N) {
      vb = *(const float4*)(B + (size_t)c*ldb + k0 + lk);
      if (DUAL) vb2 = *(const float4*)(B + (size_t)c*ldb + boff + k0 + lk);
    }
    Bs0[lk+0][lr]=vb.x; Bs0[lk+1][lr]=vb.y; Bs0[lk+2][lr]=vb.z; Bs0[lk+3][lr]=vb.w;
    if (DUAL) {
      Bs1[lk+0][lr]=vb2.x-vb.x; Bs1[lk+1][lr]=vb2.y-vb.y;
      Bs1[lk+2][lr]=vb2.z-vb.z; Bs1[lk+3][lr]=vb2.w-vb.w;
    }
    __syncthreads();
    #pragma unroll
    for (int kk=0;kk<16;kk++){
      float4 a  = *(const float4*)&As[kk][ty*4];
      float4 b0 = *(const float4*)&Bs0[kk][tx*4];
      float av[4]={a.x,a.y,a.z,a.w};
      float b0v[4]={b0.x,b0.y,b0.z,b0.w};
      #pragma unroll
      for (int i=0;i<4;i++)
        #pragma unroll
        for (int j=0;j<4;j++) acc0[i][j] = fmaf(av[i], b0v[j], acc0[i][j]);
      if (DUAL) {
        float4 b1 = *(const float4*)&Bs1[kk][tx*4];
        float b1v[4]={b1.x,b1.y,b1.z,b1.w};
        #pragma unroll
        for (int i=0;i<4;i++)
          #pragma unroll
          for (int j=0;j<4;j++) acc1[i][j] = fmaf(av[i], b1v[j], acc1[i][j]);
      }
    }
    __syncthreads();
  }
  #pragma unroll
  for (int i=0;i<4;i++){
    int r = rowBase + ty*4 + i;
    if (r < M) {
      #pragma unroll
      for (int j=0;j<4;j++){
        int c = colBase + tx*4 + j;
        if (c < N) {
          o0[(size_t)r*ldo + c] = acc0[i][j];
          if (DUAL) o1[(size_t)r*ldo + c] = acc1[i][j];
        }
      }
    }
  }
}

// ---------------- gather + max over K neighbors (+ optional adds) ----------------
__global__ __launch_bounds__(256) void gathermax_kernel(
    const float* __restrict__ P, const int* __restrict__ nbr,
    const float* __restrict__ addA, const float* __restrict__ addB,
    float* __restrict__ out, int n_out, int n_src, int O, int K, int total)
{
  int e = blockIdx.x*256 + threadIdx.x;
  if (e >= total) return;
  int o = e % O; int r = e / O;
  int b = r / n_out; int i = r % n_out;
  const int* nb = nbr + ((size_t)b*n_out + i)*K;
  float mx = -1e38f;
  for (int k=0;k<K;k++){
    int j = nb[k];
    float v = P[((size_t)b*n_src + j)*O + o];
    mx = fmaxf(mx, v);
  }
  float res = mx;
  if (addA) res += addA[e];
  if (addB) res = addB[e] + res;
  out[e] = res;
}

// ---------------- deterministic per-channel stats ----------------
__global__ void stats_part_kernel(const float* __restrict__ x, int R, int O,
                                  float* __restrict__ part)
{
  int o = threadIdx.x;
  int chunk = blockIdx.x;
  int per = (R + NCHUNK - 1)/NCHUNK;
  int r0 = chunk*per, r1 = min(r0+per, R);
  float s=0, q=0;
  for (int r=r0; r<r1; r++){ float v = x[(size_t)r*O + o]; s+=v; q+=v*v; }
  part[(size_t)chunk*1024 + o] = s;
  part[(size_t)(NCHUNK+chunk)*1024 + o] = q;
}

__global__ void stats_final_kernel(const float* __restrict__ part, float* __restrict__ st)
{
  int o = threadIdx.x;
  float s=0, q=0;
  #pragma unroll 4
  for (int c=0;c<NCHUNK;c++){
    s += part[(size_t)c*1024 + o];
    q += part[(size_t)(NCHUNK+c)*1024 + o];
  }
  st[o] = s; st[512+o] = q;
}

__global__ __launch_bounds__(256) void bngelu_kernel(float* __restrict__ x,
    const float* __restrict__ st, float invR, int O, int total)
{
  int e = blockIdx.x*256 + threadIdx.x;
  if (e >= total) return;
  int o = e % O;
  float mu = st[o]*invR;
  float var = st[512+o]*invR - mu*mu;
  float v = (x[e]-mu) / sqrtf(var + 1e-5f);
  x[e] = gelu_f(v);
}

// ---------------- initial 3->64 MLP ----------------
__global__ __launch_bounds__(256) void mlp_kernel(const float* __restrict__ x,
    const float* __restrict__ w, const float* __restrict__ bias,
    float* __restrict__ out, int N, int total)
{
  int e = blockIdx.x*256 + threadIdx.x;
  if (e >= total) return;
  int o = e & 63; int r = e >> 6;
  int b = r / N; int i = r % N;
  const float* xb = x + (size_t)b*3*N;
  float v = ((w[o*3+0]*xb[i] + w[o*3+1]*xb[N+i]) + w[o*3+2]*xb[2*N+i]) + bias[o];
  out[e] = v;
}

// ---------------- mean over 8 neighbors for xyz downsample ----------------
__global__ __launch_bounds__(256) void cur_mean_kernel(const float* __restrict__ cur,
    const int* __restrict__ nbr, float* __restrict__ outc, int n, int m, int total)
{
  int e = blockIdx.x*256 + threadIdx.x;
  if (e >= total) return;
  int i = e % m; int d = (e/m)%3; int b = e/(3*m);
  const int* nb = nbr + ((size_t)b*m + i)*8;
  const float* cb = cur + (size_t)b*3*n + (size_t)d*n;
  float s=0;
  #pragma unroll
  for (int k=0;k<8;k++) s += cb[nb[k]];
  outc[(size_t)b*3*m + (size_t)d*m + i] = s * 0.125f;
}

// ---------------- per-point squared norms ----------------
__global__ __launch_bounds__(256) void norms_kernel(const float* __restrict__ h,
    float* __restrict__ aa, int C, int total)
{
  int e = blockIdx.x*256 + threadIdx.x;
  if (e >= total) return;
  const float* r = h + (size_t)e*C;
  float s=0;
  for (int c=0;c<C;c++) s += r[c]*r[c];
  aa[e]=s;
}

// ---------------- head ----------------
__global__ __launch_bounds__(1024) void head_kernel(const float* __restrict__ h,
    const float* __restrict__ w1, const float* __restrict__ w2,
    const float* __restrict__ b2, float* __restrict__ out)
{
  __shared__ __align__(16) float g[4*512];
  __shared__ __align__(16) float t[4*256];
  int tid = threadIdx.x;
  for (int e=tid; e<2048; e+=1024){
    int b=e>>9, c=e&511;
    float s=0;
    for (int p=0;p<16;p++) s += h[((size_t)(b*16+p))*512 + c];
    g[e] = s * (1.0f/16.0f);
  }
  __syncthreads();
  {
    int b = tid>>8, j = tid&255;
    const float4* gr = (const float4*)(g + b*512);
    const float4* wr = (const float4*)(w1 + (size_t)j*512);
    float s=0;
    for (int c=0;c<128;c++){
      float4 a=gr[c], w=wr[c];
      s = fmaf(a.x,w.x, fmaf(a.y,w.y, fmaf(a.z,w.z, fmaf(a.w,w.w, s))));
    }
    t[tid] = s;
  }
  __syncthreads();
  if (tid < 256){
    float v0=t[tid], v1=t[256+tid], v2=t[512+tid], v3=t[768+tid];
    float mu = ((v0+v1)+v2+v3)*0.25f;
    float d0=v0-mu, d1=v1-mu, d2=v2-mu, d3=v3-mu;
    float var = ((d0*d0+d1*d1)+d2*d2+d3*d3)*0.25f;
    float sq = sqrtf(var + 1e-5f);
    t[tid]     = gelu_f(d0/sq);
    t[256+tid] = gelu_f(d1/sq);
    t[512+tid] = gelu_f(d2/sq);
    t[768+tid] = gelu_f(d3/sq);
  }
  __syncthreads();
  if (tid < 160){
    int b = tid/40, o = tid%40;
    const float* tr = t + b*256; const float* wr = w2 + (size_t)o*256;
    float s=0;
    for (int j=0;j<256;j++) s = fmaf(tr[j], wr[j], s);
    out[tid] = s + b2[o];
  }
}

// =====================================================================
extern "C" void kernel_launch(void* const* d_in, const int* in_sizes, int n_in,
                              void* d_out, int out_size, void* d_ws, size_t ws_size,
                              hipStream_t stream)
{
  const float* x    = (const float*)d_in[0];
  const float* xyz  = (const float*)d_in[1];
  const float* mlpw = (const float*)d_in[2];
  const float* mlpb = (const float*)d_in[3];
  const float* c0l1 = (const float*)d_in[4];
  const float* c0l2 = (const float*)d_in[5];
  const float* L1[4] = {(const float*)d_in[6], (const float*)d_in[8],
                        (const float*)d_in[11], (const float*)d_in[14]};
  const float* L2[4] = {(const float*)d_in[7], (const float*)d_in[9],
                        (const float*)d_in[12], (const float*)d_in[15]};
  const float* SC[4] = {nullptr, (const float*)d_in[10],
                        (const float*)d_in[13], (const float*)d_in[16]};
  const float* hw1 = (const float*)d_in[17];
  const float* hw2 = (const float*)d_in[18];
  const float* hb2 = (const float*)d_in[19];
  float* out = (float*)d_out;

  float* ws = (float*)d_ws;
  const size_t MF = 1024*1024;
  float* D    = ws;               // 4M floats (pdist Gram)
  float* hA   = ws + 4*MF;
  float* hX   = ws + 5*MF;
  float* hP   = ws + 6*MF;
  float* hCT  = ws + 7*MF;
  float* hSH  = ws + 8*MF;
  float* hH1  = ws + 9*MF;
  float* hOUT = ws + 10*MF;
  int*   nbr0 = (int*)(ws + 11*MF);
  int*   nbrS = (int*)(ws + 11*MF + 400000);
  int*   nbrF = (int*)(ws + 11*MF + 450000);
  int*   sind = (int*)(ws + 11*MF + 500000);
  float* aa   = ws + 11*MF + 520000;
  float* cur1 = ws + 11*MF + 540000;
  float* cur2 = ws + 11*MF + 600000;
  float* stats= ws + 11*MF + 660000;   // 12 slots * 1024 floats
  float* part = ws + 11*MF + 680000;   // 2*NCHUNK*1024 floats scratch

  // ---- kNN on xyz, k=16, wave-per-query ----
  knn_wave<16><<<dim3(4096/4, 4),256,0,stream>>>(xyz, 4096, xyz, nullptr, 4096, nbr0);

  auto bnstats = [&](const float* buf, int R, int O, float* slot){
    stats_part_kernel<<<NCHUNK, O, 0, stream>>>(buf, R, O, part);
    stats_final_kernel<<<1, O, 0, stream>>>(part, slot);
  };

  // initial MLP + BN + gelu
  int tot0 = 4*4096*64;
  mlp_kernel<<<(tot0+255)/256,256,0,stream>>>(x, mlpw, mlpb, hA, 4096, tot0);
  bnstats(hA, 16384, 64, stats+0*1024);
  bngelu_kernel<<<(tot0+255)/256,256,0,stream>>>(hA, stats+0*1024, 1.0f/16384.0f, 64, tot0);

  auto edgeconv = [&](const float* xin, const int* nbr, int K, int n, int Cin, int O1, int O2,
                      const float* l1, const float* l2, const float* sc,
                      int slot1, int slot2, float* outbuf)
  {
    int R = 4*n;
    dim3 gg1((O1+63)/64, (R+63)/64, 1);
    gemm_nt<true><<<gg1,256,0,stream>>>(xin, l1, hP, hCT, R, O1, Cin, Cin, 2*Cin, O1, Cin, 0,0,0);
    int t1 = R*O1;
    gathermax_kernel<<<(t1+255)/256,256,0,stream>>>(hP, nbr, hCT, nullptr, hH1, n, n, O1, K, t1);
    bnstats(hH1, R, O1, stats+(size_t)slot1*1024);
    bngelu_kernel<<<(t1+255)/256,256,0,stream>>>(hH1, stats+(size_t)slot1*1024, 1.0f/R, O1, t1);

    dim3 gg2((O2+63)/64, (R+63)/64, 1);
    gemm_nt<true><<<gg2,256,0,stream>>>(hH1, l2, hP, hCT, R, O2, O1, O1, 2*O1, O2, O1, 0,0,0);
    const float* addB;
    if (sc) {
      gemm_nt<false><<<gg2,256,0,stream>>>(xin, sc, hSH, nullptr, R, O2, Cin, Cin, Cin, O2, 0, 0,0,0);
      addB = hSH;
    } else addB = xin;
    int t2 = R*O2;
    gathermax_kernel<<<(t2+255)/256,256,0,stream>>>(hP, nbr, hCT, addB, outbuf, n, n, O2, K, t2);
    bnstats(outbuf, R, O2, stats+(size_t)slot2*1024);
    bngelu_kernel<<<(t2+255)/256,256,0,stream>>>(outbuf, stats+(size_t)slot2*1024, 1.0f/R, O2, t2);
  };

  // first edge conv (uses xyz-kNN), x = hA
  edgeconv(hA, nbr0, 16, 4096, 64, 64, 64, c0l1, c0l2, nullptr, 1, 2, hOUT);
  float* hcur = hOUT;

  const float* cur = xyz; int nprev = 4096;
  int NPTSa[4] = {1024,256,64,16};
  int CinA[4] = {64,64,128,256}, O1A[4]={64,128,256,512}, O2A[4]={64,128,256,512};
  float* curbuf[2] = {cur1, cur2};

  for (int s=0;s<4;s++){
    int m = NPTSa[s];
    // ---- FPS: 4 waves, spill-free, tree argmax ----
    if (nprev==4096)      fps_mw<16,256,1024><<<4,256,0,stream>>>(cur, nprev, sind);
    else if (nprev==1024) fps_mw<4,256,256><<<4,256,0,stream>>>(cur, nprev, sind);
    else if (nprev==256)  fps_mw<1,256,64><<<4,256,0,stream>>>(cur, nprev, sind);
    else                  fps_mw<1,64,16><<<4,64,0,stream>>>(cur, nprev, sind);
    // ---- kNN of sampled points vs all prev points, k=8, wave-per-query ----
    knn_wave<8><<<dim3(m/4,4),256,0,stream>>>(cur, nprev, cur, sind, m, nbrS);
    // xyz downsample (mean of 8 nbrs)
    int tc = 4*3*m;
    cur_mean_kernel<<<(tc+255)/256,256,0,stream>>>(cur, nbrS, curbuf[s&1], nprev, m, tc);
    // feature downsample (max of 8 nbrs)
    int th = 4*m*CinA[s];
    gathermax_kernel<<<(th+255)/256,256,0,stream>>>(hcur, nbrS, nullptr, nullptr, hX, m, nprev, CinA[s], 8, th);
    // feature-space kNN: norms + Gram + wave top-8
    norms_kernel<<<(4*m+255)/256,256,0,stream>>>(hX, aa, CinA[s], 4*m);
    dim3 gp((m+63)/64, (m+63)/64, 4);
    gemm_nt<false><<<gp,256,0,stream>>>(hX, hX, D, nullptr, m, m, CinA[s],
                                        CinA[s], CinA[s], m, 0,
                                        (long)m*CinA[s], (long)m*CinA[s], (long)m*m);
    topk_wave<8><<<dim3(m/4,4),256,0,stream>>>(D, aa, m, nbrF);
    // edge conv
    float* outbuf = (s&1) ? hOUT : hA;
    edgeconv(hX, nbrF, 8, m, CinA[s], O1A[s], O2A[s], L1[s], L2[s], SC[s],
             3+2*s, 4+2*s, outbuf);
    hcur = outbuf;
    cur = curbuf[s&1]; nprev = m;
  }

  head_kernel<<<1,1024,0,stream>>>(hcur, hw1, hw2, hb2, out);
}

// Round 6
// 2245.877 us; speedup vs baseline: 3.3490x; 1.0656x over previous
//
#include <hip/hip_runtime.h>
#include <math.h>

#define NCHUNK 32
typedef unsigned long long ull;

__device__ __forceinline__ float gelu_f(float v){
  return 0.5f*v*(1.0f+erff(v*0.70710678118654752440f));
}

__device__ __forceinline__ unsigned flipf(float d){
  unsigned u = __float_as_uint(d);
  return (u & 0x80000000u) ? ~u : (u | 0x80000000u);
}

// ---- DPP/swizzle wave reductions on u64 keys (exact, order-independent) ----
// XOR1=quad_perm[1,0,3,2](0xB1), XOR2=quad_perm[2,3,0,1](0x4E),
// XOR7(within 8)=row_half_mirror(0x141), XOR15(within16)=row_mirror(0x140),
// XOR16=ds_swizzle 0x401F, cross-32 via readlane 0/32 -> uniform result.
template<int CTRL>
__device__ __forceinline__ ull kmax_dpp(ull k){
  int lo = __builtin_amdgcn_update_dpp(0, (int)(unsigned)k,       CTRL, 0xF, 0xF, true);
  int hi = __builtin_amdgcn_update_dpp(0, (int)(unsigned)(k>>32), CTRL, 0xF, 0xF, true);
  ull o = ((ull)(unsigned)hi<<32) | (unsigned)lo;
  return o > k ? o : k;
}
__device__ __forceinline__ ull kmax_swz(ull k){
  int lo = __builtin_amdgcn_ds_swizzle((int)(unsigned)k,       0x401F);
  int hi = __builtin_amdgcn_ds_swizzle((int)(unsigned)(k>>32), 0x401F);
  ull o = ((ull)(unsigned)hi<<32) | (unsigned)lo;
  return o > k ? o : k;
}
__device__ __forceinline__ ull wave_kmax(ull k){
  k = kmax_dpp<0xB1>(k);
  k = kmax_dpp<0x4E>(k);
  k = kmax_dpp<0x141>(k);
  k = kmax_dpp<0x140>(k);
  k = kmax_swz(k);
  unsigned lo0 = (unsigned)__builtin_amdgcn_readlane((int)(unsigned)k, 0);
  unsigned hi0 = (unsigned)__builtin_amdgcn_readlane((int)(unsigned)(k>>32), 0);
  unsigned lo1 = (unsigned)__builtin_amdgcn_readlane((int)(unsigned)k, 32);
  unsigned hi1 = (unsigned)__builtin_amdgcn_readlane((int)(unsigned)(k>>32), 32);
  ull k0 = ((ull)hi0<<32)|lo0, k1 = ((ull)hi1<<32)|lo1;
  return k0 > k1 ? k0 : k1;
}
template<int CTRL>
__device__ __forceinline__ ull kmin_dpp(ull k){
  int lo = __builtin_amdgcn_update_dpp(0, (int)(unsigned)k,       CTRL, 0xF, 0xF, true);
  int hi = __builtin_amdgcn_update_dpp(0, (int)(unsigned)(k>>32), CTRL, 0xF, 0xF, true);
  ull o = ((ull)(unsigned)hi<<32) | (unsigned)lo;
  return o < k ? o : k;
}
__device__ __forceinline__ ull kmin_swz(ull k){
  int lo = __builtin_amdgcn_ds_swizzle((int)(unsigned)k,       0x401F);
  int hi = __builtin_amdgcn_ds_swizzle((int)(unsigned)(k>>32), 0x401F);
  ull o = ((ull)(unsigned)hi<<32) | (unsigned)lo;
  return o < k ? o : k;
}
__device__ __forceinline__ ull wave_kmin(ull k){
  k = kmin_dpp<0xB1>(k);
  k = kmin_dpp<0x4E>(k);
  k = kmin_dpp<0x141>(k);
  k = kmin_dpp<0x140>(k);
  k = kmin_swz(k);
  unsigned lo0 = (unsigned)__builtin_amdgcn_readlane((int)(unsigned)k, 0);
  unsigned hi0 = (unsigned)__builtin_amdgcn_readlane((int)(unsigned)(k>>32), 0);
  unsigned lo1 = (unsigned)__builtin_amdgcn_readlane((int)(unsigned)k, 32);
  unsigned hi1 = (unsigned)__builtin_amdgcn_readlane((int)(unsigned)(k>>32), 32);
  ull k0 = ((ull)hi0<<32)|lo0, k1 = ((ull)hi1<<32)|lo1;
  return k0 < k1 ? k0 : k1;
}

// ============ wave-per-query kNN in 3D (optional fused cur-mean, K==8) ============
// key = (flip(d)<<32) | idx ; lex order == (d asc, idx asc) == stable top_k order.
template<int K>
__global__ __launch_bounds__(256) void knn_wave(
    const float* __restrict__ cand, int n,
    const float* __restrict__ qsrc, const int* __restrict__ qidx, int m,
    int* __restrict__ nbr, float* __restrict__ outc)
{
  __shared__ float cx[1024], cy[1024], cz[1024], cbb[1024];
  int b = blockIdx.y;
  int wv = threadIdx.x >> 6, lane = threadIdx.x & 63;
  int q = blockIdx.x*4 + wv;           // m is always a multiple of 4
  const float* cb = cand + (size_t)b*3*n;
  int qi = qidx ? qidx[(size_t)b*m + q] : q;
  const float* qb = qsrc + (size_t)b*3*n;
  float qx = qb[qi], qy = qb[n+qi], qz = qb[2*n+qi];
  float aa = (qx*qx + qy*qy) + qz*qz;

  ull a[K];
  #pragma unroll
  for (int k=0;k<K;k++) a[k] = ~0ull;
  ull worst = ~0ull; int wslot = 0;

  for (int base=0; base<n; base+=1024){
    int cnt = min(1024, n-base);
    for (int j=threadIdx.x; j<cnt; j+=256){
      float x=cb[base+j], y=cb[n+base+j], z=cb[2*n+base+j];
      cx[j]=x; cy[j]=y; cz[j]=z; cbb[j]=(x*x+y*y)+z*z;
    }
    __syncthreads();
    int steps = cnt >> 6;
    for (int i=0;i<steps;i++){
      int j = lane + (i<<6);
      float d = aa + cbb[j] - 2.0f*((qx*cx[j]+qy*cy[j])+qz*cz[j]);
      ull key = ((ull)flipf(d)<<32) | (unsigned)(base+j);
      if (key < worst){
        #pragma unroll
        for (int k=0;k<K;k++) if (k==wslot) a[k] = key;
        worst = a[0]; wslot = 0;
        #pragma unroll
        for (int k=1;k<K;k++){
          bool g = a[k] > worst;
          worst = g ? a[k] : worst;
          wslot = g ? k : wslot;
        }
      }
    }
    __syncthreads();
  }

  // per-lane bitonic sort ascending
  #pragma unroll
  for (int kk=2; kk<=K; kk<<=1)
    #pragma unroll
    for (int jj=kk>>1; jj>0; jj>>=1)
      #pragma unroll
      for (int i=0;i<K;i++){
        int l = i ^ jj;
        if (l > i){
          bool dirUp = ((i & kk) == 0);
          ull x = a[i], y = a[l];
          bool sw = dirUp ? (x > y) : (x < y);
          a[i] = sw ? y : x;
          a[l] = sw ? x : y;
        }
      }

  // K rounds of wave-min extraction (DPP) with sorted-list pop
  ull head = a[0];
  int res[K];
  #pragma unroll
  for (int r=0; r<K; r++){
    ull mk = wave_kmin(head);        // uniform
    res[r] = (int)(unsigned)mk;
    if (head == mk){
      #pragma unroll
      for (int i2=0;i2<K-1;i2++) a[i2]=a[i2+1];
      a[K-1] = ~0ull;
      head = a[0];
    }
  }
  if (lane == 0){
    int* o = nbr + ((size_t)b*m + q)*K;
    #pragma unroll
    for (int r=0;r<K;r++) o[r] = res[r];
  }
  // fused xyz-downsample mean (only used for K==8 sampled-kNN)
  if (outc != nullptr && lane < 3){
    const float* cd = cb + (size_t)lane*n;
    float s=0;
    #pragma unroll
    for (int k=0;k<K;k++) s += cd[res[k]];
    outc[((size_t)b*3 + lane)*m + q] = s * (1.0f/K);
  }
}

// ============ wave-per-query top-K from Gram rows (coalesced) ============
template<int K>
__global__ __launch_bounds__(256) void topk_wave(
    const float* __restrict__ G, const float* __restrict__ aa, int m,
    int* __restrict__ nbr)
{
  __shared__ float abs_s[1024];
  int b = blockIdx.y;
  int wv = threadIdx.x >> 6, lane = threadIdx.x & 63;
  int q = blockIdx.x*4 + wv;
  const float* ab = aa + (size_t)b*m;
  for (int j=threadIdx.x; j<m; j+=256) abs_s[j] = ab[j];
  __syncthreads();
  float aq = ab[q];
  const float* Gq = G + ((size_t)b*m + q)*m;   // row; bitwise symmetric Gram

  ull a[K];
  #pragma unroll
  for (int k=0;k<K;k++) a[k] = ~0ull;
  ull worst = ~0ull; int wslot = 0;

  int steps = (m+63)>>6;
  for (int i=0;i<steps;i++){
    int j = lane + (i<<6);
    ull key = ~0ull;
    if (j < m){
      float g = Gq[j];
      float d = aq + abs_s[j] - 2.0f*g;
      key = ((ull)flipf(d)<<32) | (unsigned)j;
    }
    if (key < worst){
      #pragma unroll
      for (int k=0;k<K;k++) if (k==wslot) a[k] = key;
      worst = a[0]; wslot = 0;
      #pragma unroll
      for (int k=1;k<K;k++){
        bool g = a[k] > worst;
        worst = g ? a[k] : worst;
        wslot = g ? k : wslot;
      }
    }
  }

  #pragma unroll
  for (int kk=2; kk<=K; kk<<=1)
    #pragma unroll
    for (int jj=kk>>1; jj>0; jj>>=1)
      #pragma unroll
      for (int i=0;i<K;i++){
        int l = i ^ jj;
        if (l > i){
          bool dirUp = ((i & kk) == 0);
          ull x = a[i], y = a[l];
          bool sw = dirUp ? (x > y) : (x < y);
          a[i] = sw ? y : x;
          a[l] = sw ? x : y;
        }
      }

  ull head = a[0];
  int res[K];
  #pragma unroll
  for (int r=0; r<K; r++){
    ull mk = wave_kmin(head);
    res[r] = (int)(unsigned)mk;
    if (head == mk){
      #pragma unroll
      for (int i2=0;i2<K-1;i2++) a[i2]=a[i2+1];
      a[K-1] = ~0ull;
      head = a[0];
    }
  }
  if (lane == 0){
    int* o = nbr + ((size_t)b*m + q)*K;
    #pragma unroll
    for (int r=0;r<K;r++) o[r] = res[r];
  }
}

// ============ multi-wave FPS with DPP wave argmax ============
// key = (nd_bits<<32) | ~j : nd>=0 so bits order-monotone; max -> max d, ties -> min j.
template<int NP, int T, int M>
__global__ __launch_bounds__(T,1) void fps_mw(const float* __restrict__ cur, int n,
                                              int* __restrict__ sind)
{
  constexpr int NW = T/64;
  int b = blockIdx.x, tid = threadIdx.x;
  int wv = tid>>6;
  const float* cb = cur + (size_t)b*3*n;
  __shared__ float4 lp[NP*T];
  __shared__ ull wred[2][NW];
  float px[NP], py[NP], pz[NP], dmin[NP];
  unsigned nj[NP];
  #pragma unroll
  for (int s=0;s<NP;s++){
    int j = tid + s*T;
    px[s]=cb[j]; py[s]=cb[n+j]; pz[s]=cb[2*n+j]; dmin[s]=1e30f;
    nj[s] = (unsigned)(~j);
    lp[j] = make_float4(px[s],py[s],pz[s],0.f);
  }
  __syncthreads();
  float X = lp[0].x, Y = lp[0].y, Z = lp[0].z;
  if (tid==0) sind[(size_t)b*M] = 0;
  int p = 0;
  for (int step=1; step<M; step++){
    ull key[NP];
    #pragma unroll
    for (int s=0;s<NP;s++){
      float dx=px[s]-X, dy=py[s]-Y, dz=pz[s]-Z;
      float d = (dx*dx + dy*dy) + dz*dz;
      float nd = fminf(dmin[s], d);
      dmin[s] = nd;
      key[s] = ((ull)__float_as_uint(nd)<<32) | nj[s];
    }
    #pragma unroll
    for (int w=NP; w>1; w>>=1)
      #pragma unroll
      for (int i=0;i<NP;i++) if (i < (w>>1))
        key[i] = key[i] >= key[i+(w>>1)] ? key[i] : key[i+(w>>1)];
    ull wk = wave_kmax(key[0]);      // uniform per wave
    if ((tid&63)==0) wred[p][wv] = wk;
    __syncthreads();
    ull gk = wred[p][0];
    #pragma unroll
    for (int w=1;w<NW;w++){
      ull o = wred[p][w];
      gk = gk >= o ? gk : o;
    }
    int gi = (int)(~(unsigned)gk);
    if (tid==0) sind[(size_t)b*M + step] = gi;
    float4 wp = lp[gi];
    X=wp.x; Y=wp.y; Z=wp.z;
    p ^= 1;
  }
}

// ---------------- tiled NT GEMM ----------------
template<bool DUAL>
__global__ __launch_bounds__(256) void gemm_nt(
    const float* __restrict__ A, const float* __restrict__ B,
    float* __restrict__ out0, float* __restrict__ out1,
    int M, int N, int Kd, int lda, int ldb, int ldo, int boff,
    long sA, long sB, long sO)
{
  int bz = blockIdx.z;
  A += (size_t)bz * sA; B += (size_t)bz * sB;
  float* o0 = out0 + (size_t)bz * sO;
  float* o1 = DUAL ? (out1 + (size_t)bz * sO) : nullptr;
  int rowBase = blockIdx.y*64, colBase = blockIdx.x*64;
  __shared__ float As[16][64], Bs0[16][64];
  __shared__ float Bs1[DUAL?16:1][64];
  int tid = threadIdx.x;
  int ty = tid>>4, tx = tid&15;
  float acc0[4][4] = {}, acc1[4][4] = {};
  int lr = tid>>2, lk = (tid&3)*4;
  for (int k0=0; k0<Kd; k0+=16) {
    float4 va = make_float4(0,0,0,0);
    int r = rowBase + lr;
    if (r < M) va = *(const float4*)(A + (size_t)r*lda + k0 + lk);
    As[lk+0][lr]=va.x; As[lk+1][lr]=va.y; As[lk+2][lr]=va.z; As[lk+3][lr]=va.w;
    float4 vb = make_float4(0,0,0,0), vb2 = make_float4(0,0,0,0);
    int c = colBase + lr;
    if (c < N) {
      vb = *(const float4*)(B + (size_t)c*ldb + k0 + lk);
      if (DUAL) vb2 = *(const float4*)(B + (size_t)c*ldb + boff + k0 + lk);
    }
    Bs0[lk+0][lr]=vb.x; Bs0[lk+1][lr]=vb.y; Bs0[lk+2][lr]=vb.z; Bs0[lk+3][lr]=vb.w;
    if (DUAL) {
      Bs1[lk+0][lr]=vb2.x-vb.x; Bs1[lk+1][lr]=vb2.y-vb.y;
      Bs1[lk+2][lr]=vb2.z-vb.z; Bs1[lk+3][lr]=vb2.w-vb.w;
    }
    __syncthreads();
    #pragma unroll
    for (int kk=0;kk<16;kk++){
      float4 a  = *(const float4*)&As[kk][ty*4];
      float4 b0 = *(const float4*)&Bs0[kk][tx*4];
      float av[4]={a.x,a.y,a.z,a.w};
      float b0v[4]={b0.x,b0.y,b0.z,b0.w};
      #pragma unroll
      for (int i=0;i<4;i++)
        #pragma unroll
        for (int j=0;j<4;j++) acc0[i][j] = fmaf(av[i], b0v[j], acc0[i][j]);
      if (DUAL) {
        float4 b1 = *(const float4*)&Bs1[kk][tx*4];
        float b1v[4]={b1.x,b1.y,b1.z,b1.w};
        #pragma unroll
        for (int i=0;i<4;i++)
          #pragma unroll
          for (int j=0;j<4;j++) acc1[i][j] = fmaf(av[i], b1v[j], acc1[i][j]);
      }
    }
    __syncthreads();
  }
  #pragma unroll
  for (int i=0;i<4;i++){
    int r = rowBase + ty*4 + i;
    if (r < M) {
      #pragma unroll
      for (int j=0;j<4;j++){
        int c = colBase + tx*4 + j;
        if (c < N) {
          o0[(size_t)r*ldo + c] = acc0[i][j];
          if (DUAL) o1[(size_t)r*ldo + c] = acc1[i][j];
        }
      }
    }
  }
}

// ---------------- gather + max over K neighbors (+ optional adds) ----------------
__global__ __launch_bounds__(256) void gathermax_kernel(
    const float* __restrict__ P, const int* __restrict__ nbr,
    const float* __restrict__ addA, const float* __restrict__ addB,
    float* __restrict__ out, int n_out, int n_src, int O, int K, int total)
{
  int e = blockIdx.x*256 + threadIdx.x;
  if (e >= total) return;
  int o = e % O; int r = e / O;
  int b = r / n_out; int i = r % n_out;
  const int* nb = nbr + ((size_t)b*n_out + i)*K;
  float mx = -1e38f;
  for (int k=0;k<K;k++){
    int j = nb[k];
    float v = P[((size_t)b*n_src + j)*O + o];
    mx = fmaxf(mx, v);
  }
  float res = mx;
  if (addA) res += addA[e];
  if (addB) res = addB[e] + res;
  out[e] = res;
}

// ---------------- deterministic per-channel stats (partials only) ----------------
__global__ void stats_part_kernel(const float* __restrict__ x, int R, int O,
                                  float* __restrict__ part)
{
  int o = threadIdx.x;
  int chunk = blockIdx.x;
  int per = (R + NCHUNK - 1)/NCHUNK;
  int r0 = chunk*per, r1 = min(r0+per, R);
  float s=0, q=0;
  for (int r=r0; r<r1; r++){ float v = x[(size_t)r*O + o]; s+=v; q+=v*v; }
  part[(size_t)chunk*1024 + o] = s;
  part[(size_t)(NCHUNK+chunk)*1024 + o] = q;
}

// fused finalize (fixed-order chunk sum, bit-identical to previous 2-kernel path)
__global__ __launch_bounds__(256) void bngelu_kernel(float* __restrict__ x,
    const float* __restrict__ part, float invR, int O, int total)
{
  __shared__ float mu_s[512], var_s[512];
  for (int oo=threadIdx.x; oo<O; oo+=256){
    float s=0, q=0;
    #pragma unroll 4
    for (int c=0;c<NCHUNK;c++){
      s += part[(size_t)c*1024 + oo];
      q += part[(size_t)(NCHUNK+c)*1024 + oo];
    }
    float mu = s*invR;
    mu_s[oo] = mu;
    var_s[oo] = q*invR - mu*mu;
  }
  __syncthreads();
  int e = blockIdx.x*256 + threadIdx.x;
  if (e >= total) return;
  int o = e % O;
  float v = (x[e]-mu_s[o]) / sqrtf(var_s[o] + 1e-5f);
  x[e] = gelu_f(v);
}

// ---------------- initial 3->64 MLP ----------------
__global__ __launch_bounds__(256) void mlp_kernel(const float* __restrict__ x,
    const float* __restrict__ w, const float* __restrict__ bias,
    float* __restrict__ out, int N, int total)
{
  int e = blockIdx.x*256 + threadIdx.x;
  if (e >= total) return;
  int o = e & 63; int r = e >> 6;
  int b = r / N; int i = r % N;
  const float* xb = x + (size_t)b*3*N;
  float v = ((w[o*3+0]*xb[i] + w[o*3+1]*xb[N+i]) + w[o*3+2]*xb[2*N+i]) + bias[o];
  out[e] = v;
}

// ---------------- per-point squared norms ----------------
__global__ __launch_bounds__(256) void norms_kernel(const float* __restrict__ h,
    float* __restrict__ aa, int C, int total)
{
  int e = blockIdx.x*256 + threadIdx.x;
  if (e >= total) return;
  const float* r = h + (size_t)e*C;
  float s=0;
  for (int c=0;c<C;c++) s += r[c]*r[c];
  aa[e]=s;
}

// ---------------- head ----------------
__global__ __launch_bounds__(1024) void head_kernel(const float* __restrict__ h,
    const float* __restrict__ w1, const float* __restrict__ w2,
    const float* __restrict__ b2, float* __restrict__ out)
{
  __shared__ __align__(16) float g[4*512];
  __shared__ __align__(16) float t[4*256];
  int tid = threadIdx.x;
  for (int e=tid; e<2048; e+=1024){
    int b=e>>9, c=e&511;
    float s=0;
    for (int p=0;p<16;p++) s += h[((size_t)(b*16+p))*512 + c];
    g[e] = s * (1.0f/16.0f);
  }
  __syncthreads();
  {
    int b = tid>>8, j = tid&255;
    const float4* gr = (const float4*)(g + b*512);
    const float4* wr = (const float4*)(w1 + (size_t)j*512);
    float s=0;
    for (int c=0;c<128;c++){
      float4 a=gr[c], w=wr[c];
      s = fmaf(a.x,w.x, fmaf(a.y,w.y, fmaf(a.z,w.z, fmaf(a.w,w.w, s))));
    }
    t[tid] = s;
  }
  __syncthreads();
  if (tid < 256){
    float v0=t[tid], v1=t[256+tid], v2=t[512+tid], v3=t[768+tid];
    float mu = ((v0+v1)+v2+v3)*0.25f;
    float d0=v0-mu, d1=v1-mu, d2=v2-mu, d3=v3-mu;
    float var = ((d0*d0+d1*d1)+d2*d2+d3*d3)*0.25f;
    float sq = sqrtf(var + 1e-5f);
    t[tid]     = gelu_f(d0/sq);
    t[256+tid] = gelu_f(d1/sq);
    t[512+tid] = gelu_f(d2/sq);
    t[768+tid] = gelu_f(d3/sq);
  }
  __syncthreads();
  if (tid < 160){
    int b = tid/40, o = tid%40;
    const float* tr = t + b*256; const float* wr = w2 + (size_t)o*256;
    float s=0;
    for (int j=0;j<256;j++) s = fmaf(tr[j], wr[j], s);
    out[tid] = s + b2[o];
  }
}

// =====================================================================
extern "C" void kernel_launch(void* const* d_in, const int* in_sizes, int n_in,
                              void* d_out, int out_size, void* d_ws, size_t ws_size,
                              hipStream_t stream)
{
  const float* x    = (const float*)d_in[0];
  const float* xyz  = (const float*)d_in[1];
  const float* mlpw = (const float*)d_in[2];
  const float* mlpb = (const float*)d_in[3];
  const float* c0l1 = (const float*)d_in[4];
  const float* c0l2 = (const float*)d_in[5];
  const float* L1[4] = {(const float*)d_in[6], (const float*)d_in[8],
                        (const float*)d_in[11], (const float*)d_in[14]};
  const float* L2[4] = {(const float*)d_in[7], (const float*)d_in[9],
                        (const float*)d_in[12], (const float*)d_in[15]};
  const float* SC[4] = {nullptr, (const float*)d_in[10],
                        (const float*)d_in[13], (const float*)d_in[16]};
  const float* hw1 = (const float*)d_in[17];
  const float* hw2 = (const float*)d_in[18];
  const float* hb2 = (const float*)d_in[19];
  float* out = (float*)d_out;

  float* ws = (float*)d_ws;
  const size_t MF = 1024*1024;
  float* D    = ws;               // 4M floats (pdist Gram)
  float* hA   = ws + 4*MF;
  float* hX   = ws + 5*MF;
  float* hP   = ws + 6*MF;
  float* hCT  = ws + 7*MF;
  float* hSH  = ws + 8*MF;
  float* hH1  = ws + 9*MF;
  float* hOUT = ws + 10*MF;
  int*   nbr0 = (int*)(ws + 11*MF);
  int*   nbrS = (int*)(ws + 11*MF + 400000);
  int*   nbrF = (int*)(ws + 11*MF + 450000);
  int*   sind = (int*)(ws + 11*MF + 500000);
  float* aa   = ws + 11*MF + 520000;
  float* cur1 = ws + 11*MF + 540000;
  float* cur2 = ws + 11*MF + 600000;
  float* part = ws + 11*MF + 680000;   // 2*NCHUNK*1024 floats scratch

  // ---- kNN on xyz, k=16, wave-per-query ----
  knn_wave<16><<<dim3(4096/4, 4),256,0,stream>>>(xyz, 4096, xyz, nullptr, 4096, nbr0, nullptr);

  // initial MLP + BN + gelu
  int tot0 = 4*4096*64;
  mlp_kernel<<<(tot0+255)/256,256,0,stream>>>(x, mlpw, mlpb, hA, 4096, tot0);
  stats_part_kernel<<<NCHUNK, 64, 0, stream>>>(hA, 16384, 64, part);
  bngelu_kernel<<<(tot0+255)/256,256,0,stream>>>(hA, part, 1.0f/16384.0f, 64, tot0);

  auto edgeconv = [&](const float* xin, const int* nbr, int K, int n, int Cin, int O1, int O2,
                      const float* l1, const float* l2, const float* sc,
                      float* outbuf)
  {
    int R = 4*n;
    dim3 gg1((O1+63)/64, (R+63)/64, 1);
    gemm_nt<true><<<gg1,256,0,stream>>>(xin, l1, hP, hCT, R, O1, Cin, Cin, 2*Cin, O1, Cin, 0,0,0);
    int t1 = R*O1;
    gathermax_kernel<<<(t1+255)/256,256,0,stream>>>(hP, nbr, hCT, nullptr, hH1, n, n, O1, K, t1);
    stats_part_kernel<<<NCHUNK, O1, 0, stream>>>(hH1, R, O1, part);
    bngelu_kernel<<<(t1+255)/256,256,0,stream>>>(hH1, part, 1.0f/R, O1, t1);

    dim3 gg2((O2+63)/64, (R+63)/64, 1);
    gemm_nt<true><<<gg2,256,0,stream>>>(hH1, l2, hP, hCT, R, O2, O1, O1, 2*O1, O2, O1, 0,0,0);
    const float* addB;
    if (sc) {
      gemm_nt<false><<<gg2,256,0,stream>>>(xin, sc, hSH, nullptr, R, O2, Cin, Cin, Cin, O2, 0, 0,0,0);
      addB = hSH;
    } else addB = xin;
    int t2 = R*O2;
    gathermax_kernel<<<(t2+255)/256,256,0,stream>>>(hP, nbr, hCT, addB, outbuf, n, n, O2, K, t2);
    stats_part_kernel<<<NCHUNK, O2, 0, stream>>>(outbuf, R, O2, part);
    bngelu_kernel<<<(t2+255)/256,256,0,stream>>>(outbuf, part, 1.0f/R, O2, t2);
  };

  // first edge conv (uses xyz-kNN), x = hA
  edgeconv(hA, nbr0, 16, 4096, 64, 64, 64, c0l1, c0l2, nullptr, hOUT);
  float* hcur = hOUT;

  const float* cur = xyz; int nprev = 4096;
  int NPTSa[4] = {1024,256,64,16};
  int CinA[4] = {64,64,128,256}, O1A[4]={64,128,256,512}, O2A[4]={64,128,256,512};
  float* curbuf[2] = {cur1, cur2};

  for (int s=0;s<4;s++){
    int m = NPTSa[s];
    // ---- FPS: DPP wave argmax ----
    if (nprev==4096)      fps_mw<8,512,1024><<<4,512,0,stream>>>(cur, nprev, sind);
    else if (nprev==1024) fps_mw<2,512,256><<<4,512,0,stream>>>(cur, nprev, sind);
    else if (nprev==256)  fps_mw<1,256,64><<<4,256,0,stream>>>(cur, nprev, sind);
    else                  fps_mw<1,64,16><<<4,64,0,stream>>>(cur, nprev, sind);
    // ---- kNN of sampled points vs prev points, k=8 (+ fused xyz mean) ----
    knn_wave<8><<<dim3(m/4,4),256,0,stream>>>(cur, nprev, cur, sind, m, nbrS, curbuf[s&1]);
    // feature downsample (max of 8 nbrs)
    int th = 4*m*CinA[s];
    gathermax_kernel<<<(th+255)/256,256,0,stream>>>(hcur, nbrS, nullptr, nullptr, hX, m, nprev, CinA[s], 8, th);
    // feature-space kNN: norms + Gram + wave top-8
    norms_kernel<<<(4*m+255)/256,256,0,stream>>>(hX, aa, CinA[s], 4*m);
    dim3 gp((m+63)/64, (m+63)/64, 4);
    gemm_nt<false><<<gp,256,0,stream>>>(hX, hX, D, nullptr, m, m, CinA[s],
                                        CinA[s], CinA[s], m, 0,
                                        (long)m*CinA[s], (long)m*CinA[s], (long)m*m);
    topk_wave<8><<<dim3(m/4,4),256,0,stream>>>(D, aa, m, nbrF);
    // edge conv
    float* outbuf = (s&1) ? hOUT : hA;
    edgeconv(hX, nbrF, 8, m, CinA[s], O1A[s], O2A[s], L1[s], L2[s], SC[s], outbuf);
    hcur = outbuf;
    cur = curbuf[s&1]; nprev = m;
  }

  head_kernel<<<1,1024,0,stream>>>(hcur, hw1, hw2, hb2, out);
}